// Round 5
// baseline (1073.899 us; speedup 1.0000x reference)
//
#include <hip/hip_runtime.h>

// RelativeBPEWORDFusionMultiheadAttention on MI355X (gfx950). FP32 in/out.
// Precision plan: the fused path M·A_word·M^T amplifies iid elementwise error
// by ~170x, so every quantity on that chain (q_word,k_word,awt,C1,M) is kept
// at fp32 quality via Dekker hi/lo bf16 splits + 3-pass MFMA (hh+hl+lh,
// rel err ~2^-17). Logits buffer fp32. Unamplified paths (q/k_bpe, V, AO,
// outproj) stay single bf16.

#define DEV __device__ __forceinline__

typedef unsigned short u16;
typedef __attribute__((ext_vector_type(8))) short short8;
typedef __attribute__((ext_vector_type(4))) float floatx4;

DEV float bf2f(u16 u) { union { unsigned u; float f; } v; v.u = ((unsigned)u) << 16; return v.f; }
DEV u16 f2bf(float f) {
  union { float f; unsigned u; } v; v.f = f;
  unsigned r = v.u + 0x7FFFu + ((v.u >> 16) & 1u);  // RNE
  return (u16)(r >> 16);
}

// ---------------- GEMM core: 128x128 tile, BK=32, 4 waves (2x2), 64x64/wave ----
// LDS tile [128][32] bf16; 16B-chunk XOR swizzle. Staging modes:
// 0 = bf16 passthrough, 1 = fp32 -> bf16 (hi), 2 = fp32 -> bf16 residual (lo).
template <int MODE>
DEV void stage_tile_m(const void* g, int ld, u16* lds, int tid) {
#pragma unroll
  for (int p = 0; p < 2; ++p) {
    int o = (p * 256 + tid) * 16;     // LDS byte offset (linear fill)
    int r = o >> 6;                   // tile row (64B per row)
    int c = (o >> 4) & 3;             // 16B chunk within row
    int sc = c ^ ((r >> 1) & 3);      // swizzle via source permutation
    if constexpr (MODE == 0) {
      *(short8*)((char*)lds + o) = *(const short8*)((const u16*)g + (size_t)r * ld + sc * 8);
    } else {
      const float* src = (const float*)g + (size_t)r * ld + sc * 8;
      union { short8 s; u16 u[8]; } out;
#pragma unroll
      for (int j = 0; j < 8; ++j) {
        float f = src[j];
        u16 h = f2bf(f);
        out.u[j] = (MODE == 1) ? h : f2bf(f - bf2f(h));
      }
      *(short8*)((char*)lds + o) = out.s;
    }
  }
}

DEV short8 frag_ld(const u16* lds, int row, int quad) {
  int c = quad ^ ((row >> 1) & 3);
  return *(const short8*)(lds + row * 32 + c * 8);
}

template <int AM, int BM>
DEV void gemm_loop(const void* A, int lda, const void* B, int ldb, int K,
                   u16* As, u16* Bs, int tid, floatx4 acc[4][4]) {
  const int lane = tid & 63, wv = tid >> 6;
  const int wr = wv >> 1, wc = wv & 1;
  const int m = lane & 15, quad = lane >> 4;
  for (int k0 = 0; k0 < K; k0 += 32) {
    __syncthreads();
    stage_tile_m<AM>((const char*)A + (size_t)k0 * (AM ? 4 : 2), lda, As, tid);
    stage_tile_m<BM>((const char*)B + (size_t)k0 * (BM ? 4 : 2), ldb, Bs, tid);
    __syncthreads();
    short8 af[4], bf[4];
#pragma unroll
    for (int t = 0; t < 4; ++t) af[t] = frag_ld(As, wr * 64 + t * 16 + m, quad);
#pragma unroll
    for (int t = 0; t < 4; ++t) bf[t] = frag_ld(Bs, wc * 64 + t * 16 + m, quad);
#pragma unroll
    for (int rt = 0; rt < 4; ++rt)
#pragma unroll
      for (int ct = 0; ct < 4; ++ct)
        acc[rt][ct] = __builtin_amdgcn_mfma_f32_16x16x32_bf16(af[rt], bf[ct], acc[rt][ct], 0, 0, 0);
  }
}

DEV void acc_zero(floatx4 acc[4][4]) {
  floatx4 z = {0.f, 0.f, 0.f, 0.f};
#pragma unroll
  for (int i = 0; i < 4; ++i)
#pragma unroll
    for (int j = 0; j < 4; ++j) acc[i][j] = z;
}

// ---------------- bpe projections (single bf16): q_bpe, k_bpe, V(->VT) --------
struct ProjArgs {
  const float* X; int T;
  const float* W[3]; const float* bias[3]; float scale[3];
  u16* dst[3]; u16* dst_lo[3]; int vt[3];
};

__global__ __launch_bounds__(256) void proj_kernel(ProjArgs a) {
  __shared__ __align__(16) u16 As[128 * 32], Bs[128 * 32];
  const int tid = threadIdx.x, z = blockIdx.z;
  const float* A = a.X + (size_t)blockIdx.y * 128 * 1024;
  const float* B = a.W[z] + (size_t)blockIdx.x * 128 * 1024;
  floatx4 acc[4][4];
  acc_zero(acc);
  gemm_loop<1, 1>(A, 1024, B, 1024, 1024, As, Bs, tid, acc);
  const int lane = tid & 63, wv = tid >> 6, wr = wv >> 1, wc = wv & 1;
  const int m = lane & 15, quad = lane >> 4;
  const float scale = a.scale[z];
  const float* bias = a.bias[z];
  u16* dst = a.dst[z];
  const int vt = a.vt[z];
  const int row0 = blockIdx.y * 128 + wr * 64 + quad * 4;
  const int col0 = blockIdx.x * 128 + wc * 64 + m;
#pragma unroll
  for (int rt = 0; rt < 4; ++rt)
#pragma unroll
    for (int ct = 0; ct < 4; ++ct) {
      int col = col0 + ct * 16;
      float bi = bias[col];
      int h = col >> 6, d = col & 63;
#pragma unroll
      for (int rg = 0; rg < 4; ++rg) {
        int row = row0 + rt * 16 + rg;
        int t = row >> 2, bb = row & 3;
        int n = bb * 16 + h;
        float val = (acc[rt][ct][rg] + bi) * scale;
        if (vt) dst[((size_t)n * 64 + d) * 1024 + t] = f2bf(val);           // VT[n][d][t]
        else    dst[((size_t)n * a.T + t) * 64 + d] = f2bf(val);            // [n][t][d]
      }
    }
}

// ---------------- word projections (hi/lo split in, hi/lo out) ----------------
__global__ __launch_bounds__(256) void proj_word_kernel(ProjArgs a) {
  __shared__ __align__(16) u16 As[128 * 32], Bs[128 * 32];
  const int tid = threadIdx.x, z = blockIdx.z;
  const float* A = a.X + (size_t)blockIdx.y * 128 * 1024;
  const float* B = a.W[z] + (size_t)blockIdx.x * 128 * 1024;
  floatx4 acc[4][4];
  acc_zero(acc);
  gemm_loop<1, 1>(A, 1024, B, 1024, 1024, As, Bs, tid, acc);
  gemm_loop<1, 2>(A, 1024, B, 1024, 1024, As, Bs, tid, acc);
  gemm_loop<2, 1>(A, 1024, B, 1024, 1024, As, Bs, tid, acc);
  const int lane = tid & 63, wv = tid >> 6, wr = wv >> 1, wc = wv & 1;
  const int m = lane & 15, quad = lane >> 4;
  const float scale = a.scale[z];
  const float* bias = a.bias[z];
  u16* dsth = a.dst[z];
  u16* dstl = a.dst_lo[z];
  const int row0 = blockIdx.y * 128 + wr * 64 + quad * 4;
  const int col0 = blockIdx.x * 128 + wc * 64 + m;
#pragma unroll
  for (int rt = 0; rt < 4; ++rt)
#pragma unroll
    for (int ct = 0; ct < 4; ++ct) {
      int col = col0 + ct * 16;
      float bi = bias[col];
      int h = col >> 6, d = col & 63;
#pragma unroll
      for (int rg = 0; rg < 4; ++rg) {
        int row = row0 + rt * 16 + rg;
        int t = row >> 2, bb = row & 3;
        size_t idx = ((size_t)(bb * 16 + h) * a.T + t) * 64 + d;
        float val = (acc[rt][ct][rg] + bi) * scale;
        u16 hh = f2bf(val);
        dsth[idx] = hh;
        dstl[idx] = f2bf(val - bf2f(hh));
      }
    }
}

// ---------------- M split: mapping fp32 -> Mh, Ml bf16 ----------------
__global__ __launch_bounds__(256) void msplit_kernel(const float* __restrict__ M,
                                                     u16* __restrict__ Mh, u16* __restrict__ Ml) {
  int i = blockIdx.x * 256 + threadIdx.x;
  float f = M[i];
  u16 h = f2bf(f);
  Mh[i] = h;
  Ml[i] = f2bf(f - bf2f(h));
}

// ---------------- rel logits: R[nt][r] = q[nt,:] . relk[r,:] (q = hi+lo) -------
__global__ __launch_bounds__(256) void rel_kernel(const u16* __restrict__ qh, const u16* __restrict__ ql,
                                                  const float* __restrict__ relk,
                                                  float* __restrict__ R, int total_rows) {
  int nt = blockIdx.x * 256 + threadIdx.x;
  if (nt >= total_rows) return;
  float qv[64];
#pragma unroll
  for (int c = 0; c < 8; ++c) {
    union { short8 s; u16 u[8]; } uh; uh.s = *(const short8*)(qh + (size_t)nt * 64 + c * 8);
#pragma unroll
    for (int j = 0; j < 8; ++j) qv[c * 8 + j] = bf2f(uh.u[j]);
  }
  if (ql) {
#pragma unroll
    for (int c = 0; c < 8; ++c) {
      union { short8 s; u16 u[8]; } ul; ul.s = *(const short8*)(ql + (size_t)nt * 64 + c * 8);
#pragma unroll
      for (int j = 0; j < 8; ++j) qv[c * 8 + j] += bf2f(ul.u[j]);
    }
  }
  for (int r = 0; r < 33; ++r) {
    const float* krow = relk + r * 64;
    float s = 0.f;
#pragma unroll
    for (int d = 0; d < 64; ++d) s += qv[d] * krow[d];
    R[(size_t)nt * 33 + r] = s;
  }
}

// ------ word scores (transposed, hi/lo): awt[nl][s][w] = attn_word[n][w][s] ----
__global__ __launch_bounds__(256) void wordscore_kernel(const u16* __restrict__ kh, const u16* __restrict__ kl,
                                                        const u16* __restrict__ qh, const u16* __restrict__ ql,
                                                        const float* __restrict__ Rw,
                                                        u16* __restrict__ ah, u16* __restrict__ al, int n0) {
  __shared__ __align__(16) u16 As[128 * 32], Bs[128 * 32];
  const int tid = threadIdx.x, nl = blockIdx.z, n = n0 + nl;
  const size_t ka = ((size_t)n * 512 + blockIdx.y * 128) * 64;  // rows s
  const size_t qa = ((size_t)n * 512 + blockIdx.x * 128) * 64;  // rows w
  floatx4 acc[4][4];
  acc_zero(acc);
  gemm_loop<0, 0>(kh + ka, 64, qh + qa, 64, 64, As, Bs, tid, acc);
  gemm_loop<0, 0>(kh + ka, 64, ql + qa, 64, 64, As, Bs, tid, acc);
  gemm_loop<0, 0>(kl + ka, 64, qh + qa, 64, 64, As, Bs, tid, acc);
  const int lane = tid & 63, wv = tid >> 6, wr = wv >> 1, wc = wv & 1;
  const int m = lane & 15, quad = lane >> 4;
  const int s0 = blockIdx.y * 128 + wr * 64 + quad * 4;
  const int w0 = blockIdx.x * 128 + wc * 64 + m;
#pragma unroll
  for (int rt = 0; rt < 4; ++rt)
#pragma unroll
    for (int ct = 0; ct < 4; ++ct) {
      int w = w0 + ct * 16;
#pragma unroll
      for (int rg = 0; rg < 4; ++rg) {
        int s = s0 + rt * 16 + rg;
        int id = s - w; id = id < -16 ? -16 : (id > 16 ? 16 : id); id += 16;
        float val = acc[rt][ct][rg] + Rw[((size_t)n * 512 + w) * 33 + id];
        size_t idx = ((size_t)nl * 512 + s) * 512 + w;
        u16 hh = f2bf(val);
        ah[idx] = hh;
        al[idx] = f2bf(val - bf2f(hh));
      }
    }
}

// ------ stage1 (hi/lo): C1[nl][q][s] = sum_w M[b][q][w] * awt[nl][s][w] --------
__global__ __launch_bounds__(256) void stage1_kernel(const u16* __restrict__ Mh, const u16* __restrict__ Ml,
                                                     const u16* __restrict__ ah, const u16* __restrict__ al,
                                                     u16* __restrict__ ch, u16* __restrict__ cl, int n0) {
  __shared__ __align__(16) u16 As[128 * 32], Bs[128 * 32];
  const int tid = threadIdx.x, nl = blockIdx.z, n = n0 + nl, b = n >> 4;
  const size_t ma = ((size_t)b * 1024 + blockIdx.y * 128) * 512;   // rows q
  const size_t aa = ((size_t)nl * 512 + blockIdx.x * 128) * 512;   // rows s
  floatx4 acc[4][4];
  acc_zero(acc);
  gemm_loop<0, 0>(Mh + ma, 512, ah + aa, 512, 512, As, Bs, tid, acc);
  gemm_loop<0, 0>(Mh + ma, 512, al + aa, 512, 512, As, Bs, tid, acc);
  gemm_loop<0, 0>(Ml + ma, 512, ah + aa, 512, 512, As, Bs, tid, acc);
  const int lane = tid & 63, wv = tid >> 6, wr = wv >> 1, wc = wv & 1;
  const int m = lane & 15, quad = lane >> 4;
  const int q0 = blockIdx.y * 128 + wr * 64 + quad * 4;
  const int s0 = blockIdx.x * 128 + wc * 64 + m;
#pragma unroll
  for (int rt = 0; rt < 4; ++rt)
#pragma unroll
    for (int ct = 0; ct < 4; ++ct) {
      int s = s0 + ct * 16;
#pragma unroll
      for (int rg = 0; rg < 4; ++rg) {
        int q = q0 + rt * 16 + rg;
        size_t idx = ((size_t)nl * 1024 + q) * 512 + s;
        float val = acc[rt][ct][rg];
        u16 hh = f2bf(val);
        ch[idx] = hh;
        cl[idx] = f2bf(val - bf2f(hh));
      }
    }
}

// ------ logits: L[nl][q][k] = qb.kb + C1@M^T + rel  (fp32) ---------------------
__global__ __launch_bounds__(256) void logits_kernel(const u16* __restrict__ qb, const u16* __restrict__ kb,
                                                     const u16* __restrict__ ch, const u16* __restrict__ cl,
                                                     const u16* __restrict__ Mh, const u16* __restrict__ Ml,
                                                     const float* __restrict__ Rb, float* __restrict__ L,
                                                     int n0) {
  __shared__ __align__(16) u16 As[128 * 32], Bs[128 * 32];
  const int tid = threadIdx.x, nl = blockIdx.z, n = n0 + nl, b = n >> 4;
  const size_t qa = ((size_t)n * 1024 + blockIdx.y * 128) * 64;
  const size_t ka = ((size_t)n * 1024 + blockIdx.x * 128) * 64;
  const size_t ca = ((size_t)nl * 1024 + blockIdx.y * 128) * 512;
  const size_t ma = ((size_t)b * 1024 + blockIdx.x * 128) * 512;
  floatx4 acc[4][4];
  acc_zero(acc);
  gemm_loop<0, 0>(qb + qa, 64, kb + ka, 64, 64, As, Bs, tid, acc);
  gemm_loop<0, 0>(ch + ca, 512, Mh + ma, 512, 512, As, Bs, tid, acc);
  gemm_loop<0, 0>(ch + ca, 512, Ml + ma, 512, 512, As, Bs, tid, acc);
  gemm_loop<0, 0>(cl + ca, 512, Mh + ma, 512, 512, As, Bs, tid, acc);
  const int lane = tid & 63, wv = tid >> 6, wr = wv >> 1, wc = wv & 1;
  const int m = lane & 15, quad = lane >> 4;
  const int q0 = blockIdx.y * 128 + wr * 64 + quad * 4;
  const int k0 = blockIdx.x * 128 + wc * 64 + m;
#pragma unroll
  for (int rt = 0; rt < 4; ++rt)
#pragma unroll
    for (int ct = 0; ct < 4; ++ct) {
      int kc = k0 + ct * 16;
#pragma unroll
      for (int rg = 0; rg < 4; ++rg) {
        int q = q0 + rt * 16 + rg;
        int id = kc - q; id = id < -16 ? -16 : (id > 16 ? 16 : id); id += 16;
        float val = acc[rt][ct][rg] + Rb[((size_t)n * 1024 + q) * 33 + id];
        L[((size_t)nl * 1024 + q) * 1024 + kc] = val;
      }
    }
}

// ---------------- softmax + PV (online; fp32 logits in A-frag layout) ----------
__global__ __launch_bounds__(256) void softmax_pv_kernel(const float* __restrict__ L,
                                                         const u16* __restrict__ VT,
                                                         u16* __restrict__ AO, int n0) {
  __shared__ __align__(16) u16 Vs[64 * 128];  // [d][kc] tile, 16B-chunk swizzled
  const int tid = threadIdx.x, lane = tid & 63, wv = tid >> 6;
  const int m = lane & 15, quad = lane >> 4;
  const int nl = blockIdx.y, n = n0 + nl, qt = blockIdx.x;
  const int qrow = qt * 64 + wv * 16 + m;  // this lane's softmax row
  const float* Lrow = L + ((size_t)nl * 1024 + qrow) * 1024;
  const u16* Vbase = VT + (size_t)n * 64 * 1024;
  float mi = -1e30f, li = 0.f;
  floatx4 O[4];
  floatx4 z = {0.f, 0.f, 0.f, 0.f};
#pragma unroll
  for (int dt = 0; dt < 4; ++dt) O[dt] = z;

  for (int kt = 0; kt < 8; ++kt) {
    __syncthreads();
#pragma unroll
    for (int p = 0; p < 4; ++p) {  // stage VT tile [64][128]
      int o = (p * 256 + tid) * 16;
      int d = o >> 8;
      int c = (o >> 4) & 15;
      int sc = c ^ (d & 7);
      *(short8*)((char*)Vs + o) = *(const short8*)(Vbase + (size_t)d * 1024 + kt * 128 + sc * 8);
    }
    __syncthreads();

    float vals[4][8];
#pragma unroll
    for (int ct = 0; ct < 4; ++ct) {
      const floatx4* p4 = (const floatx4*)(Lrow + kt * 128 + ct * 32 + quad * 8);
      floatx4 v0 = p4[0], v1 = p4[1];
#pragma unroll
      for (int j = 0; j < 4; ++j) { vals[ct][j] = v0[j]; vals[ct][4 + j] = v1[j]; }
    }
    float tmax = vals[0][0];
#pragma unroll
    for (int ct = 0; ct < 4; ++ct)
#pragma unroll
      for (int j = 0; j < 8; ++j) tmax = fmaxf(tmax, vals[ct][j]);
    tmax = fmaxf(tmax, __shfl_xor(tmax, 16));
    tmax = fmaxf(tmax, __shfl_xor(tmax, 32));
    float mnew = fmaxf(mi, tmax);
    float alpha = __expf(mi - mnew);
    float pv[4][8];
    float tsum = 0.f;
#pragma unroll
    for (int ct = 0; ct < 4; ++ct)
#pragma unroll
      for (int j = 0; j < 8; ++j) { pv[ct][j] = __expf(vals[ct][j] - mnew); tsum += pv[ct][j]; }
    tsum += __shfl_xor(tsum, 16);
    tsum += __shfl_xor(tsum, 32);
    li = li * alpha + tsum;
    mi = mnew;

    float ar[4];
#pragma unroll
    for (int rg = 0; rg < 4; ++rg) ar[rg] = __shfl(alpha, quad * 4 + rg);
#pragma unroll
    for (int dt = 0; dt < 4; ++dt)
#pragma unroll
      for (int rg = 0; rg < 4; ++rg) O[dt][rg] *= ar[rg];

    short8 pf[4];
#pragma unroll
    for (int ct = 0; ct < 4; ++ct) {
      union { short8 s; u16 us[8]; } up;
#pragma unroll
      for (int j = 0; j < 8; ++j) up.us[j] = f2bf(pv[ct][j]);
      pf[ct] = up.s;
    }
#pragma unroll
    for (int ct = 0; ct < 4; ++ct)
#pragma unroll
      for (int dt = 0; dt < 4; ++dt) {
        int vrow = dt * 16 + m;
        int chunk = (ct * 4 + quad) ^ (vrow & 7);
        short8 vf = *(const short8*)((const u16*)Vs + vrow * 128 + chunk * 8);
        O[dt] = __builtin_amdgcn_mfma_f32_16x16x32_bf16(pf[ct], vf, O[dt], 0, 0, 0);
      }
  }

  float linv = 1.f / li;
  float lr[4];
#pragma unroll
  for (int rg = 0; rg < 4; ++rg) lr[rg] = __shfl(linv, quad * 4 + rg);
  const int b = n >> 4, h = n & 15;
#pragma unroll
  for (int dt = 0; dt < 4; ++dt)
#pragma unroll
    for (int rg = 0; rg < 4; ++rg) {
      int q = qt * 64 + wv * 16 + quad * 4 + rg;
      float ov = O[dt][rg] * lr[rg];
      AO[((size_t)q * 4 + b) * 1024 + h * 64 + dt * 16 + m] = f2bf(ov);
    }
}

// ---------------- output projection: out = AO @ Wo^T + bo  (fp32 out) ----------
__global__ __launch_bounds__(256) void outproj_kernel(const u16* __restrict__ AO, const float* __restrict__ Wo,
                                                      const float* __restrict__ bo, float* __restrict__ out) {
  __shared__ __align__(16) u16 As[128 * 32], Bs[128 * 32];
  const int tid = threadIdx.x;
  floatx4 acc[4][4];
  acc_zero(acc);
  gemm_loop<0, 1>(AO + (size_t)blockIdx.y * 128 * 1024, 1024,
                  Wo + (size_t)blockIdx.x * 128 * 1024, 1024, 1024, As, Bs, tid, acc);
  const int lane = tid & 63, wv = tid >> 6, wr = wv >> 1, wc = wv & 1;
  const int m = lane & 15, quad = lane >> 4;
  const int r0 = blockIdx.y * 128 + wr * 64 + quad * 4;
  const int c0 = blockIdx.x * 128 + wc * 64 + m;
#pragma unroll
  for (int rt = 0; rt < 4; ++rt)
#pragma unroll
    for (int ct = 0; ct < 4; ++ct) {
      int col = c0 + ct * 16;
      float bi = bo[col];
#pragma unroll
      for (int rg = 0; rg < 4; ++rg) {
        int row = r0 + rt * 16 + rg;
        out[(size_t)row * 1024 + col] = acc[rt][ct][rg] + bi;
      }
    }
}

extern "C" void kernel_launch(void* const* d_in, const int* in_sizes, int n_in,
                              void* d_out, int out_size, void* d_ws, size_t ws_size,
                              hipStream_t stream) {
  const float* query_bpe = (const float*)d_in[0];
  const float* query_word = (const float*)d_in[1];
  const float* mapping = (const float*)d_in[2];
  const float* Wq_bpe = (const float*)d_in[3];
  const float* bq_bpe = (const float*)d_in[4];
  const float* Wk_bpe = (const float*)d_in[5];
  const float* bk_bpe = (const float*)d_in[6];
  const float* Wq_word = (const float*)d_in[7];
  const float* bq_word = (const float*)d_in[8];
  const float* Wk_word = (const float*)d_in[9];
  const float* bk_word = (const float*)d_in[10];
  const float* Wv = (const float*)d_in[11];
  const float* bv = (const float*)d_in[12];
  const float* Wo = (const float*)d_in[13];
  const float* bo = (const float*)d_in[14];
  const float* relk = (const float*)d_in[15];

  char* ws = (char*)d_ws;
  size_t off = 0;
  u16* q_bpe = (u16*)(ws + off); off += 8388608;   // [64][1024][64] bf16
  u16* k_bpe = (u16*)(ws + off); off += 8388608;
  u16* VTb   = (u16*)(ws + off); off += 8388608;   // [64][64][1024] (direct from proj)
  u16* qw_h  = (u16*)(ws + off); off += 4194304;   // [64][512][64] hi
  u16* qw_l  = (u16*)(ws + off); off += 4194304;   // lo
  u16* kw_h  = (u16*)(ws + off); off += 4194304;
  u16* kw_l  = (u16*)(ws + off); off += 4194304;
  u16* M_h   = (u16*)(ws + off); off += 4194304;   // [4][1024][512]
  u16* M_l   = (u16*)(ws + off); off += 4194304;
  float* R_word = (float*)(ws + off); off += 4325376;  // [64][512][33] fp32
  float* R_bpe  = (float*)(ws + off); off += 8650752;  // [64][1024][33] fp32
  u16* AO    = (u16*)(ws + off); off += 8388608;   // [4096][1024] bf16
  const size_t fixed_end = off;                    // ~72.4 MB

  // Variable per chunk of NC heads: awt h+l (NC*1MB), C1 h+l (NC*2MB), L fp32 (NC*4MB)
  const size_t per_nc = 7340032;  // 7 MB
  int NC = 1;
  for (int c = 64; c >= 1; c >>= 1) {
    if (fixed_end + (size_t)c * per_nc <= ws_size) { NC = c; break; }
  }
  char* vb = ws + fixed_end;
  u16* awt_h = (u16*)(vb);
  u16* awt_l = (u16*)(vb + (size_t)NC * 524288);
  u16* C1_h  = (u16*)(vb + (size_t)NC * 1048576);
  u16* C1_l  = (u16*)(vb + (size_t)NC * 2097152);
  float* L_c = (float*)(vb + (size_t)NC * 3145728);

  ProjArgs pb = {};
  pb.X = query_bpe; pb.T = 1024;
  pb.W[0] = Wq_bpe; pb.bias[0] = bq_bpe; pb.scale[0] = 0.125f; pb.dst[0] = q_bpe; pb.vt[0] = 0;
  pb.W[1] = Wk_bpe; pb.bias[1] = bk_bpe; pb.scale[1] = 1.0f;   pb.dst[1] = k_bpe; pb.vt[1] = 0;
  pb.W[2] = Wv;     pb.bias[2] = bv;     pb.scale[2] = 1.0f;   pb.dst[2] = VTb;   pb.vt[2] = 1;
  proj_kernel<<<dim3(8, 32, 3), 256, 0, stream>>>(pb);

  ProjArgs pw = {};
  pw.X = query_word; pw.T = 512;
  pw.W[0] = Wq_word; pw.bias[0] = bq_word; pw.scale[0] = 0.125f; pw.dst[0] = qw_h; pw.dst_lo[0] = qw_l;
  pw.W[1] = Wk_word; pw.bias[1] = bk_word; pw.scale[1] = 1.0f;   pw.dst[1] = kw_h; pw.dst_lo[1] = kw_l;
  proj_word_kernel<<<dim3(8, 16, 2), 256, 0, stream>>>(pw);

  msplit_kernel<<<dim3(4 * 1024 * 512 / 256), 256, 0, stream>>>(mapping, M_h, M_l);

  rel_kernel<<<dim3(64 * 1024 / 256), 256, 0, stream>>>(q_bpe, (const u16*)nullptr, relk, R_bpe, 64 * 1024);
  rel_kernel<<<dim3(64 * 512 / 256), 256, 0, stream>>>(qw_h, qw_l, relk, R_word, 64 * 512);

  for (int n0 = 0; n0 < 64; n0 += NC) {
    wordscore_kernel<<<dim3(4, 4, NC), 256, 0, stream>>>(kw_h, kw_l, qw_h, qw_l, R_word, awt_h, awt_l, n0);
    stage1_kernel<<<dim3(4, 8, NC), 256, 0, stream>>>(M_h, M_l, awt_h, awt_l, C1_h, C1_l, n0);
    logits_kernel<<<dim3(8, 8, NC), 256, 0, stream>>>(q_bpe, k_bpe, C1_h, C1_l, M_h, M_l, R_bpe, L_c, n0);
    softmax_pv_kernel<<<dim3(16, NC), 256, 0, stream>>>(L_c, VTb, AO, n0);
  }

  outproj_kernel<<<dim3(8, 32), 256, 0, stream>>>(AO, Wo, bo, (float*)d_out);
}

// Round 6
// 934.668 us; speedup vs baseline: 1.1490x; 1.1490x over previous
//
#include <hip/hip_runtime.h>

// RelativeBPEWORDFusionMultiheadAttention on MI355X (gfx950). FP32 in/out.
// Dekker hi/lo bf16 split on the M·A·M^T-amplified chain (3-set MFMA hh+hl+lh),
// now fused single-pass (stage Ah/Al/Bh/Bl once per K-step, 48 MFMA per stage)
// with async global_load_lds (16B) for all bf16 staging. All projections in
// one launch for occupancy.

#define DEV __device__ __forceinline__
#define GAS(x) ((const __attribute__((address_space(1))) unsigned*)(x))
#define LAS(x) ((__attribute__((address_space(3))) unsigned*)(x))

typedef unsigned short u16;
typedef __attribute__((ext_vector_type(8))) short short8;
typedef __attribute__((ext_vector_type(4))) float floatx4;

DEV float bf2f(u16 u) { union { unsigned u; float f; } v; v.u = ((unsigned)u) << 16; return v.f; }
DEV u16 f2bf(float f) {
  union { float f; unsigned u; } v; v.f = f;
  unsigned r = v.u + 0x7FFFu + ((v.u >> 16) & 1u);  // RNE
  return (u16)(r >> 16);
}

// ---- LDS tile [128][32] bf16, 16B-chunk XOR swizzle (source-side permute) ----
DEV void stage_bf16(const u16* g, int ld, u16* lds, int tid) {
#pragma unroll
  for (int p = 0; p < 2; ++p) {
    int o = (p * 256 + tid) * 16;
    int r = o >> 6, c = (o >> 4) & 3, sc = c ^ ((r >> 1) & 3);
    __builtin_amdgcn_global_load_lds(GAS(g + (size_t)r * ld + sc * 8),
                                     LAS((char*)lds + o), 16, 0, 0);
  }
}

DEV void stage_f32_hi(const float* g, int ld, u16* lds, int tid) {
#pragma unroll
  for (int p = 0; p < 2; ++p) {
    int o = (p * 256 + tid) * 16;
    int r = o >> 6, c = (o >> 4) & 3, sc = c ^ ((r >> 1) & 3);
    const float* src = g + (size_t)r * ld + sc * 8;
    union { short8 s; u16 u[8]; } oh;
#pragma unroll
    for (int j = 0; j < 8; ++j) oh.u[j] = f2bf(src[j]);
    *(short8*)((char*)lds + o) = oh.s;
  }
}

DEV void stage_f32_split(const float* g, int ld, u16* ldsh, u16* ldsl, int tid) {
#pragma unroll
  for (int p = 0; p < 2; ++p) {
    int o = (p * 256 + tid) * 16;
    int r = o >> 6, c = (o >> 4) & 3, sc = c ^ ((r >> 1) & 3);
    const float* src = g + (size_t)r * ld + sc * 8;
    union { short8 s; u16 u[8]; } oh, ol;
#pragma unroll
    for (int j = 0; j < 8; ++j) {
      float f = src[j];
      u16 h = f2bf(f);
      oh.u[j] = h;
      ol.u[j] = f2bf(f - bf2f(h));
    }
    *(short8*)((char*)ldsh + o) = oh.s;
    *(short8*)((char*)ldsl + o) = ol.s;
  }
}

DEV short8 frag_ld(const u16* lds, int row, int quad) {
  int c = quad ^ ((row >> 1) & 3);
  return *(const short8*)(lds + row * 32 + c * 8);
}

DEV void mma_one(const u16* As, const u16* Bs, int wr, int wc, int m, int quad, floatx4 acc[4][4]) {
  short8 af[4], bf[4];
#pragma unroll
  for (int t = 0; t < 4; ++t) af[t] = frag_ld(As, wr * 64 + t * 16 + m, quad);
#pragma unroll
  for (int t = 0; t < 4; ++t) bf[t] = frag_ld(Bs, wc * 64 + t * 16 + m, quad);
#pragma unroll
  for (int rt = 0; rt < 4; ++rt)
#pragma unroll
    for (int ct = 0; ct < 4; ++ct)
      acc[rt][ct] = __builtin_amdgcn_mfma_f32_16x16x32_bf16(af[rt], bf[ct], acc[rt][ct], 0, 0, 0);
}

DEV void mma_split(const u16* AsH, const u16* AsL, const u16* BsH, const u16* BsL,
                   int wr, int wc, int m, int quad, floatx4 acc[4][4]) {
  short8 ah[4], al[4], bh[4], bl[4];
#pragma unroll
  for (int t = 0; t < 4; ++t) {
    ah[t] = frag_ld(AsH, wr * 64 + t * 16 + m, quad);
    al[t] = frag_ld(AsL, wr * 64 + t * 16 + m, quad);
    bh[t] = frag_ld(BsH, wc * 64 + t * 16 + m, quad);
    bl[t] = frag_ld(BsL, wc * 64 + t * 16 + m, quad);
  }
#pragma unroll
  for (int rt = 0; rt < 4; ++rt)
#pragma unroll
    for (int ct = 0; ct < 4; ++ct) {
      acc[rt][ct] = __builtin_amdgcn_mfma_f32_16x16x32_bf16(ah[rt], bh[ct], acc[rt][ct], 0, 0, 0);
      acc[rt][ct] = __builtin_amdgcn_mfma_f32_16x16x32_bf16(ah[rt], bl[ct], acc[rt][ct], 0, 0, 0);
      acc[rt][ct] = __builtin_amdgcn_mfma_f32_16x16x32_bf16(al[rt], bh[ct], acc[rt][ct], 0, 0, 0);
    }
}

DEV void acc_zero(floatx4 acc[4][4]) {
  floatx4 z = {0.f, 0.f, 0.f, 0.f};
#pragma unroll
  for (int i = 0; i < 4; ++i)
#pragma unroll
    for (int j = 0; j < 4; ++j) acc[i][j] = z;
}

// ---------------- all 5 projections, one launch ----------------
// z: 0=q_bpe 1=k_bpe 2=V->VT 3=q_word(hi/lo) 4=k_word(hi/lo)
struct PAll {
  const float* X[5]; const float* W[5]; const float* bias[5];
  float scale[5]; u16* dh[5]; u16* dl[5]; int T[5]; int md[5];  // md: 0 plain, 1 VT, 2 hi/lo
};

__global__ __launch_bounds__(256) void proj_all_kernel(PAll a) {
  const int z = blockIdx.z;
  const int T = a.T[z];
  if ((int)blockIdx.y >= (T >> 5)) return;  // word slices use y<16
  __shared__ __align__(16) u16 AsH[4096], AsL[4096], BsH[4096], BsL[4096];
  const int tid = threadIdx.x;
  const int lane = tid & 63, wv = tid >> 6, wr = wv >> 1, wc = wv & 1;
  const int m = lane & 15, quad = lane >> 4;
  const float* A = a.X[z] + (size_t)blockIdx.y * 128 * 1024;
  const float* B = a.W[z] + (size_t)blockIdx.x * 128 * 1024;
  const bool split = a.md[z] == 2;
  floatx4 acc[4][4];
  acc_zero(acc);
  for (int k0 = 0; k0 < 1024; k0 += 32) {
    __syncthreads();
    if (split) {
      stage_f32_split(A + k0, 1024, AsH, AsL, tid);
      stage_f32_split(B + k0, 1024, BsH, BsL, tid);
    } else {
      stage_f32_hi(A + k0, 1024, AsH, tid);
      stage_f32_hi(B + k0, 1024, BsH, tid);
    }
    __syncthreads();
    if (split) mma_split(AsH, AsL, BsH, BsL, wr, wc, m, quad, acc);
    else       mma_one(AsH, BsH, wr, wc, m, quad, acc);
  }
  const float scale = a.scale[z];
  const float* bias = a.bias[z];
  u16* dh = a.dh[z];
  u16* dl = a.dl[z];
  const int md = a.md[z];
  const int row0 = blockIdx.y * 128 + wr * 64 + quad * 4;
  const int col0 = blockIdx.x * 128 + wc * 64 + m;
#pragma unroll
  for (int rt = 0; rt < 4; ++rt)
#pragma unroll
    for (int ct = 0; ct < 4; ++ct) {
      int col = col0 + ct * 16;
      float bi = bias[col];
      int h = col >> 6, d = col & 63;
#pragma unroll
      for (int rg = 0; rg < 4; ++rg) {
        int row = row0 + rt * 16 + rg;
        int t = row >> 2, bb = row & 3, n = bb * 16 + h;
        float val = (acc[rt][ct][rg] + bi) * scale;
        if (md == 1) {
          dh[((size_t)n * 64 + d) * 1024 + t] = f2bf(val);       // VT[n][d][t]
        } else if (md == 2) {
          size_t idx = ((size_t)n * T + t) * 64 + d;
          u16 hh = f2bf(val);
          dh[idx] = hh;
          dl[idx] = f2bf(val - bf2f(hh));
        } else {
          dh[((size_t)n * T + t) * 64 + d] = f2bf(val);
        }
      }
    }
}

// ---------------- M split ----------------
__global__ __launch_bounds__(256) void msplit_kernel(const float* __restrict__ M,
                                                     u16* __restrict__ Mh, u16* __restrict__ Ml) {
  int i = blockIdx.x * 256 + threadIdx.x;
  float f = M[i];
  u16 h = f2bf(f);
  Mh[i] = h;
  Ml[i] = f2bf(f - bf2f(h));
}

// ---------------- rel logits: R[nt][r] = q . relk[r] ----------------
__global__ __launch_bounds__(256) void rel_kernel(const u16* __restrict__ qh, const u16* __restrict__ ql,
                                                  const float* __restrict__ relk,
                                                  float* __restrict__ R, int total_rows) {
  int nt = blockIdx.x * 256 + threadIdx.x;
  if (nt >= total_rows) return;
  float qv[64];
#pragma unroll
  for (int c = 0; c < 8; ++c) {
    union { short8 s; u16 u[8]; } uh; uh.s = *(const short8*)(qh + (size_t)nt * 64 + c * 8);
#pragma unroll
    for (int j = 0; j < 8; ++j) qv[c * 8 + j] = bf2f(uh.u[j]);
  }
  if (ql) {
#pragma unroll
    for (int c = 0; c < 8; ++c) {
      union { short8 s; u16 u[8]; } ul; ul.s = *(const short8*)(ql + (size_t)nt * 64 + c * 8);
#pragma unroll
      for (int j = 0; j < 8; ++j) qv[c * 8 + j] += bf2f(ul.u[j]);
    }
  }
  for (int r = 0; r < 33; ++r) {
    const float* krow = relk + r * 64;
    float s = 0.f;
#pragma unroll
    for (int d = 0; d < 64; ++d) s += qv[d] * krow[d];
    R[(size_t)nt * 33 + r] = s;
  }
}

// ------ word scores (transposed, hi/lo out): awt[nl][s][w] = attn_word[n][w][s] ----
__global__ __launch_bounds__(256) void wordscore_kernel(const u16* __restrict__ kh, const u16* __restrict__ kl,
                                                        const u16* __restrict__ qh, const u16* __restrict__ ql,
                                                        const float* __restrict__ Rw,
                                                        u16* __restrict__ ah, u16* __restrict__ al, int n0) {
  __shared__ __align__(16) u16 AsH[4096], AsL[4096], BsH[4096], BsL[4096];
  const int tid = threadIdx.x, nl = blockIdx.z, n = n0 + nl;
  const int lane = tid & 63, wv = tid >> 6, wr = wv >> 1, wc = wv & 1;
  const int m = lane & 15, quad = lane >> 4;
  const size_t ka = ((size_t)n * 512 + blockIdx.y * 128) * 64;  // rows s
  const size_t qa = ((size_t)n * 512 + blockIdx.x * 128) * 64;  // rows w
  floatx4 acc[4][4];
  acc_zero(acc);
  for (int k0 = 0; k0 < 64; k0 += 32) {
    __syncthreads();
    stage_bf16(kh + ka + k0, 64, AsH, tid);
    stage_bf16(kl + ka + k0, 64, AsL, tid);
    stage_bf16(qh + qa + k0, 64, BsH, tid);
    stage_bf16(ql + qa + k0, 64, BsL, tid);
    __syncthreads();
    mma_split(AsH, AsL, BsH, BsL, wr, wc, m, quad, acc);
  }
  const int s0 = blockIdx.y * 128 + wr * 64 + quad * 4;
  const int w0 = blockIdx.x * 128 + wc * 64 + m;
#pragma unroll
  for (int rt = 0; rt < 4; ++rt)
#pragma unroll
    for (int ct = 0; ct < 4; ++ct) {
      int w = w0 + ct * 16;
#pragma unroll
      for (int rg = 0; rg < 4; ++rg) {
        int s = s0 + rt * 16 + rg;
        int id = s - w; id = id < -16 ? -16 : (id > 16 ? 16 : id); id += 16;
        float val = acc[rt][ct][rg] + Rw[((size_t)n * 512 + w) * 33 + id];
        size_t idx = ((size_t)nl * 512 + s) * 512 + w;
        u16 hh = f2bf(val);
        ah[idx] = hh;
        al[idx] = f2bf(val - bf2f(hh));
      }
    }
}

// ------ stage1 (hi/lo): C1[nl][q][s] = sum_w M[b][q][w] * awt[nl][s][w] --------
__global__ __launch_bounds__(256) void stage1_kernel(const u16* __restrict__ Mh, const u16* __restrict__ Ml,
                                                     const u16* __restrict__ ah, const u16* __restrict__ al,
                                                     u16* __restrict__ ch, u16* __restrict__ cl, int n0) {
  __shared__ __align__(16) u16 AsH[4096], AsL[4096], BsH[4096], BsL[4096];
  const int tid = threadIdx.x, nl = blockIdx.z, n = n0 + nl, b = n >> 4;
  const int lane = tid & 63, wv = tid >> 6, wr = wv >> 1, wc = wv & 1;
  const int m = lane & 15, quad = lane >> 4;
  const size_t ma = ((size_t)b * 1024 + blockIdx.y * 128) * 512;   // rows q
  const size_t aa = ((size_t)nl * 512 + blockIdx.x * 128) * 512;   // rows s
  floatx4 acc[4][4];
  acc_zero(acc);
  for (int k0 = 0; k0 < 512; k0 += 32) {
    __syncthreads();
    stage_bf16(Mh + ma + k0, 512, AsH, tid);
    stage_bf16(Ml + ma + k0, 512, AsL, tid);
    stage_bf16(ah + aa + k0, 512, BsH, tid);
    stage_bf16(al + aa + k0, 512, BsL, tid);
    __syncthreads();
    mma_split(AsH, AsL, BsH, BsL, wr, wc, m, quad, acc);
  }
  const int q0 = blockIdx.y * 128 + wr * 64 + quad * 4;
  const int s0 = blockIdx.x * 128 + wc * 64 + m;
#pragma unroll
  for (int rt = 0; rt < 4; ++rt)
#pragma unroll
    for (int ct = 0; ct < 4; ++ct) {
      int s = s0 + ct * 16;
#pragma unroll
      for (int rg = 0; rg < 4; ++rg) {
        int q = q0 + rt * 16 + rg;
        size_t idx = ((size_t)nl * 1024 + q) * 512 + s;
        float val = acc[rt][ct][rg];
        u16 hh = f2bf(val);
        ch[idx] = hh;
        cl[idx] = f2bf(val - bf2f(hh));
      }
    }
}

// ------ logits: L[nl][q][k] = qb.kb + C1@M^T + rel  (fp32) ---------------------
__global__ __launch_bounds__(256) void logits_kernel(const u16* __restrict__ qb, const u16* __restrict__ kb,
                                                     const u16* __restrict__ ch, const u16* __restrict__ cl,
                                                     const u16* __restrict__ Mh, const u16* __restrict__ Ml,
                                                     const float* __restrict__ Rb, float* __restrict__ L,
                                                     int n0) {
  __shared__ __align__(16) u16 AsH[4096], AsL[4096], BsH[4096], BsL[4096];
  const int tid = threadIdx.x, nl = blockIdx.z, n = n0 + nl, b = n >> 4;
  const int lane = tid & 63, wv = tid >> 6, wr = wv >> 1, wc = wv & 1;
  const int m = lane & 15, quad = lane >> 4;
  const size_t qa = ((size_t)n * 1024 + blockIdx.y * 128) * 64;
  const size_t ka = ((size_t)n * 1024 + blockIdx.x * 128) * 64;
  const size_t ca = ((size_t)nl * 1024 + blockIdx.y * 128) * 512;
  const size_t ma = ((size_t)b * 1024 + blockIdx.x * 128) * 512;
  floatx4 acc[4][4];
  acc_zero(acc);
  for (int k0 = 0; k0 < 64; k0 += 32) {  // content QK^T (single bf16)
    __syncthreads();
    stage_bf16(qb + qa + k0, 64, AsH, tid);
    stage_bf16(kb + ka + k0, 64, BsH, tid);
    __syncthreads();
    mma_one(AsH, BsH, wr, wc, m, quad, acc);
  }
  for (int k0 = 0; k0 < 512; k0 += 32) {  // C1 @ M^T (split 3-set)
    __syncthreads();
    stage_bf16(ch + ca + k0, 512, AsH, tid);
    stage_bf16(cl + ca + k0, 512, AsL, tid);
    stage_bf16(Mh + ma + k0, 512, BsH, tid);
    stage_bf16(Ml + ma + k0, 512, BsL, tid);
    __syncthreads();
    mma_split(AsH, AsL, BsH, BsL, wr, wc, m, quad, acc);
  }
  const int q0 = blockIdx.y * 128 + wr * 64 + quad * 4;
  const int k0c = blockIdx.x * 128 + wc * 64 + m;
#pragma unroll
  for (int rt = 0; rt < 4; ++rt)
#pragma unroll
    for (int ct = 0; ct < 4; ++ct) {
      int kc = k0c + ct * 16;
#pragma unroll
      for (int rg = 0; rg < 4; ++rg) {
        int q = q0 + rt * 16 + rg;
        int id = kc - q; id = id < -16 ? -16 : (id > 16 ? 16 : id); id += 16;
        float val = acc[rt][ct][rg] + Rb[((size_t)n * 1024 + q) * 33 + id];
        L[((size_t)nl * 1024 + q) * 1024 + kc] = val;
      }
    }
}

// ---------------- softmax + PV (online; fp32 logits in A-frag layout) ----------
__global__ __launch_bounds__(256) void softmax_pv_kernel(const float* __restrict__ L,
                                                         const u16* __restrict__ VT,
                                                         u16* __restrict__ AO, int n0) {
  __shared__ __align__(16) u16 Vs[64 * 128];  // [d][kc] tile, 16B-chunk swizzled
  const int tid = threadIdx.x, lane = tid & 63, wv = tid >> 6;
  const int m = lane & 15, quad = lane >> 4;
  const int nl = blockIdx.y, n = n0 + nl, qt = blockIdx.x;
  const int qrow = qt * 64 + wv * 16 + m;
  const float* Lrow = L + ((size_t)nl * 1024 + qrow) * 1024;
  const u16* Vbase = VT + (size_t)n * 64 * 1024;
  float mi = -1e30f, li = 0.f;
  floatx4 O[4];
  floatx4 z = {0.f, 0.f, 0.f, 0.f};
#pragma unroll
  for (int dt = 0; dt < 4; ++dt) O[dt] = z;

  for (int kt = 0; kt < 8; ++kt) {
    __syncthreads();
#pragma unroll
    for (int p = 0; p < 4; ++p) {  // stage VT tile [64][128] async
      int o = (p * 256 + tid) * 16;
      int d = o >> 8;
      int c = (o >> 4) & 15;
      int sc = c ^ (d & 7);
      __builtin_amdgcn_global_load_lds(GAS(Vbase + (size_t)d * 1024 + kt * 128 + sc * 8),
                                       LAS((char*)Vs + o), 16, 0, 0);
    }
    __syncthreads();

    float vals[4][8];
#pragma unroll
    for (int ct = 0; ct < 4; ++ct) {
      const floatx4* p4 = (const floatx4*)(Lrow + kt * 128 + ct * 32 + quad * 8);
      floatx4 v0 = p4[0], v1 = p4[1];
#pragma unroll
      for (int j = 0; j < 4; ++j) { vals[ct][j] = v0[j]; vals[ct][4 + j] = v1[j]; }
    }
    float tmax = vals[0][0];
#pragma unroll
    for (int ct = 0; ct < 4; ++ct)
#pragma unroll
      for (int j = 0; j < 8; ++j) tmax = fmaxf(tmax, vals[ct][j]);
    tmax = fmaxf(tmax, __shfl_xor(tmax, 16));
    tmax = fmaxf(tmax, __shfl_xor(tmax, 32));
    float mnew = fmaxf(mi, tmax);
    float alpha = __expf(mi - mnew);
    float pv[4][8];
    float tsum = 0.f;
#pragma unroll
    for (int ct = 0; ct < 4; ++ct)
#pragma unroll
      for (int j = 0; j < 8; ++j) { pv[ct][j] = __expf(vals[ct][j] - mnew); tsum += pv[ct][j]; }
    tsum += __shfl_xor(tsum, 16);
    tsum += __shfl_xor(tsum, 32);
    li = li * alpha + tsum;
    mi = mnew;

    float ar[4];
#pragma unroll
    for (int rg = 0; rg < 4; ++rg) ar[rg] = __shfl(alpha, quad * 4 + rg);
#pragma unroll
    for (int dt = 0; dt < 4; ++dt)
#pragma unroll
      for (int rg = 0; rg < 4; ++rg) O[dt][rg] *= ar[rg];

    short8 pf[4];
#pragma unroll
    for (int ct = 0; ct < 4; ++ct) {
      union { short8 s; u16 us[8]; } up;
#pragma unroll
      for (int j = 0; j < 8; ++j) up.us[j] = f2bf(pv[ct][j]);
      pf[ct] = up.s;
    }
#pragma unroll
    for (int ct = 0; ct < 4; ++ct)
#pragma unroll
      for (int dt = 0; dt < 4; ++dt) {
        int vrow = dt * 16 + m;
        int chunk = (ct * 4 + quad) ^ (vrow & 7);
        short8 vf = *(const short8*)((const u16*)Vs + vrow * 128 + chunk * 8);
        O[dt] = __builtin_amdgcn_mfma_f32_16x16x32_bf16(pf[ct], vf, O[dt], 0, 0, 0);
      }
  }

  float linv = 1.f / li;
  float lr[4];
#pragma unroll
  for (int rg = 0; rg < 4; ++rg) lr[rg] = __shfl(linv, quad * 4 + rg);
  const int b = n >> 4, h = n & 15;
#pragma unroll
  for (int dt = 0; dt < 4; ++dt)
#pragma unroll
    for (int rg = 0; rg < 4; ++rg) {
      int q = qt * 64 + wv * 16 + quad * 4 + rg;
      float ov = O[dt][rg] * lr[rg];
      AO[((size_t)q * 4 + b) * 1024 + h * 64 + dt * 16 + m] = f2bf(ov);
    }
}

// ---------------- output projection: out = AO @ Wo^T + bo  (fp32 out) ----------
__global__ __launch_bounds__(256) void outproj_kernel(const u16* __restrict__ AO, const float* __restrict__ Wo,
                                                      const float* __restrict__ bo, float* __restrict__ out) {
  __shared__ __align__(16) u16 AsH[4096], BsH[4096];
  const int tid = threadIdx.x;
  const int lane = tid & 63, wv = tid >> 6, wr = wv >> 1, wc = wv & 1;
  const int m = lane & 15, quad = lane >> 4;
  const u16* A = AO + (size_t)blockIdx.y * 128 * 1024;
  const float* B = Wo + (size_t)blockIdx.x * 128 * 1024;
  floatx4 acc[4][4];
  acc_zero(acc);
  for (int k0 = 0; k0 < 1024; k0 += 32) {
    __syncthreads();
    stage_bf16(A + k0, 1024, AsH, tid);
    stage_f32_hi(B + k0, 1024, BsH, tid);
    __syncthreads();
    mma_one(AsH, BsH, wr, wc, m, quad, acc);
  }
  const int r0 = blockIdx.y * 128 + wr * 64 + quad * 4;
  const int c0 = blockIdx.x * 128 + wc * 64 + m;
#pragma unroll
  for (int rt = 0; rt < 4; ++rt)
#pragma unroll
    for (int ct = 0; ct < 4; ++ct) {
      int col = c0 + ct * 16;
      float bi = bo[col];
#pragma unroll
      for (int rg = 0; rg < 4; ++rg) {
        int row = r0 + rt * 16 + rg;
        out[(size_t)row * 1024 + col] = acc[rt][ct][rg] + bi;
      }
    }
}

extern "C" void kernel_launch(void* const* d_in, const int* in_sizes, int n_in,
                              void* d_out, int out_size, void* d_ws, size_t ws_size,
                              hipStream_t stream) {
  const float* query_bpe = (const float*)d_in[0];
  const float* query_word = (const float*)d_in[1];
  const float* mapping = (const float*)d_in[2];
  const float* Wq_bpe = (const float*)d_in[3];
  const float* bq_bpe = (const float*)d_in[4];
  const float* Wk_bpe = (const float*)d_in[5];
  const float* bk_bpe = (const float*)d_in[6];
  const float* Wq_word = (const float*)d_in[7];
  const float* bq_word = (const float*)d_in[8];
  const float* Wk_word = (const float*)d_in[9];
  const float* bk_word = (const float*)d_in[10];
  const float* Wv = (const float*)d_in[11];
  const float* bv = (const float*)d_in[12];
  const float* Wo = (const float*)d_in[13];
  const float* bo = (const float*)d_in[14];
  const float* relk = (const float*)d_in[15];

  char* ws = (char*)d_ws;
  size_t off = 0;
  u16* q_bpe = (u16*)(ws + off); off += 8388608;   // [64][1024][64] bf16
  u16* k_bpe = (u16*)(ws + off); off += 8388608;
  u16* VTb   = (u16*)(ws + off); off += 8388608;   // [64][64][1024]
  u16* qw_h  = (u16*)(ws + off); off += 4194304;   // [64][512][64] hi
  u16* qw_l  = (u16*)(ws + off); off += 4194304;
  u16* kw_h  = (u16*)(ws + off); off += 4194304;
  u16* kw_l  = (u16*)(ws + off); off += 4194304;
  u16* M_h   = (u16*)(ws + off); off += 4194304;   // [4][1024][512]
  u16* M_l   = (u16*)(ws + off); off += 4194304;
  float* R_word = (float*)(ws + off); off += 4325376;  // [64][512][33]
  float* R_bpe  = (float*)(ws + off); off += 8650752;  // [64][1024][33]
  u16* AO    = (u16*)(ws + off); off += 8388608;   // [4096][1024]
  const size_t fixed_end = off;

  const size_t per_nc = 7340032;  // awt h+l 1MB + C1 h+l 2MB + L fp32 4MB
  int NC = 1;
  for (int c = 64; c >= 1; c >>= 1) {
    if (fixed_end + (size_t)c * per_nc <= ws_size) { NC = c; break; }
  }
  char* vb = ws + fixed_end;
  u16* awt_h = (u16*)(vb);
  u16* awt_l = (u16*)(vb + (size_t)NC * 524288);
  u16* C1_h  = (u16*)(vb + (size_t)NC * 1048576);
  u16* C1_l  = (u16*)(vb + (size_t)NC * 2097152);
  float* L_c = (float*)(vb + (size_t)NC * 3145728);

  PAll pa = {};
  pa.X[0] = query_bpe;  pa.W[0] = Wq_bpe;  pa.bias[0] = bq_bpe;  pa.scale[0] = 0.125f; pa.dh[0] = q_bpe; pa.T[0] = 1024; pa.md[0] = 0;
  pa.X[1] = query_bpe;  pa.W[1] = Wk_bpe;  pa.bias[1] = bk_bpe;  pa.scale[1] = 1.0f;   pa.dh[1] = k_bpe; pa.T[1] = 1024; pa.md[1] = 0;
  pa.X[2] = query_bpe;  pa.W[2] = Wv;      pa.bias[2] = bv;      pa.scale[2] = 1.0f;   pa.dh[2] = VTb;   pa.T[2] = 1024; pa.md[2] = 1;
  pa.X[3] = query_word; pa.W[3] = Wq_word; pa.bias[3] = bq_word; pa.scale[3] = 0.125f; pa.dh[3] = qw_h; pa.dl[3] = qw_l; pa.T[3] = 512; pa.md[3] = 2;
  pa.X[4] = query_word; pa.W[4] = Wk_word; pa.bias[4] = bk_word; pa.scale[4] = 1.0f;   pa.dh[4] = kw_h; pa.dl[4] = kw_l; pa.T[4] = 512; pa.md[4] = 2;
  proj_all_kernel<<<dim3(8, 32, 5), 256, 0, stream>>>(pa);

  msplit_kernel<<<dim3(4 * 1024 * 512 / 256), 256, 0, stream>>>(mapping, M_h, M_l);

  rel_kernel<<<dim3(64 * 1024 / 256), 256, 0, stream>>>(q_bpe, (const u16*)nullptr, relk, R_bpe, 64 * 1024);
  rel_kernel<<<dim3(64 * 512 / 256), 256, 0, stream>>>(qw_h, qw_l, relk, R_word, 64 * 512);

  for (int n0 = 0; n0 < 64; n0 += NC) {
    wordscore_kernel<<<dim3(4, 4, NC), 256, 0, stream>>>(kw_h, kw_l, qw_h, qw_l, R_word, awt_h, awt_l, n0);
    stage1_kernel<<<dim3(4, 8, NC), 256, 0, stream>>>(M_h, M_l, awt_h, awt_l, C1_h, C1_l, n0);
    logits_kernel<<<dim3(8, 8, NC), 256, 0, stream>>>(q_bpe, k_bpe, C1_h, C1_l, M_h, M_l, R_bpe, L_c, n0);
    softmax_pv_kernel<<<dim3(16, NC), 256, 0, stream>>>(L_c, VTb, AO, n0);
  }

  outproj_kernel<<<dim3(8, 32), 256, 0, stream>>>(AO, Wo, bo, (float*)d_out);
}

// Round 8
// 911.537 us; speedup vs baseline: 1.1781x; 1.0254x over previous
//
#include <hip/hip_runtime.h>

// RelativeBPEWORDFusionMultiheadAttention on MI355X (gfx950). FP32 in/out.
// Factorization: attn_word = Q·K^T + Rel (rank-64 + small relative term), so
//   fused = M·A·M^T = (MQ)(MK)^T + M·Rel·M^T.
// Content path (amplified ~170x) runs Dekker-bf16 3-pass on tiny K=64 GEMMs;
// Rel path (entries ~3% of A) runs single-pass fp16; bpe/V/outproj stay bf16.
// Calibrated error model (r4/r7): predicted absmax ~0.011 vs threshold 0.041.

#define DEV __device__ __forceinline__
#define GAS(x) ((const __attribute__((address_space(1))) unsigned*)(x))
#define LAS(x) ((__attribute__((address_space(3))) unsigned*)(x))

typedef unsigned short u16;
typedef __attribute__((ext_vector_type(8))) short short8;
typedef __attribute__((ext_vector_type(8))) _Float16 half8;
typedef __attribute__((ext_vector_type(4))) float floatx4;

DEV float bf2f(u16 u) { union { unsigned u; float f; } v; v.u = ((unsigned)u) << 16; return v.f; }
DEV u16 f2bf(float f) {
  union { float f; unsigned u; } v; v.f = f;
  unsigned r = v.u + 0x7FFFu + ((v.u >> 16) & 1u);  // RNE
  return (u16)(r >> 16);
}
DEV u16 f2h_bits(float f) { union { _Float16 h; u16 u; } v; v.h = (_Float16)f; return v.u; }

// ---- LDS tile [128][32] u16, 16B-chunk XOR swizzle (source-side permute) ----
DEV void stage_u16(const u16* g, int ld, u16* lds, int tid) {
#pragma unroll
  for (int p = 0; p < 2; ++p) {
    int o = (p * 256 + tid) * 16;
    int r = o >> 6, c = (o >> 4) & 3, sc = c ^ ((r >> 1) & 3);
    __builtin_amdgcn_global_load_lds(GAS(g + (size_t)r * ld + sc * 8),
                                     LAS((char*)lds + o), 16, 0, 0);
  }
}

// one 64-row half (p=0: rows 0..63, p=1: rows 64..127) from its own source
DEV void stage_u16_half(const u16* g, int ld, u16* lds, int tid, int p) {
  int o = (p * 256 + tid) * 16;
  int r = o >> 6, c = (o >> 4) & 3, sc = c ^ ((r >> 1) & 3);
  __builtin_amdgcn_global_load_lds(GAS(g + (size_t)(r - p * 64) * ld + sc * 8),
                                   LAS((char*)lds + o), 16, 0, 0);
}

DEV void stage_f32_bf(const float* g, int ld, u16* lds, int tid) {
#pragma unroll
  for (int p = 0; p < 2; ++p) {
    int o = (p * 256 + tid) * 16;
    int r = o >> 6, c = (o >> 4) & 3, sc = c ^ ((r >> 1) & 3);
    const float* src = g + (size_t)r * ld + sc * 8;
    union { short8 s; u16 u[8]; } oh;
#pragma unroll
    for (int j = 0; j < 8; ++j) oh.u[j] = f2bf(src[j]);
    *(short8*)((char*)lds + o) = oh.s;
  }
}

DEV void stage_f32_split(const float* g, int ld, u16* ldsh, u16* ldsl, int tid) {
#pragma unroll
  for (int p = 0; p < 2; ++p) {
    int o = (p * 256 + tid) * 16;
    int r = o >> 6, c = (o >> 4) & 3, sc = c ^ ((r >> 1) & 3);
    const float* src = g + (size_t)r * ld + sc * 8;
    union { short8 s; u16 u[8]; } oh, ol;
#pragma unroll
    for (int j = 0; j < 8; ++j) {
      float f = src[j];
      u16 h = f2bf(f);
      oh.u[j] = h;
      ol.u[j] = f2bf(f - bf2f(h));
    }
    *(short8*)((char*)ldsh + o) = oh.s;
    *(short8*)((char*)ldsl + o) = ol.s;
  }
}

DEV short8 frag_ld(const u16* lds, int row, int quad) {
  int c = quad ^ ((row >> 1) & 3);
  return *(const short8*)(lds + row * 32 + c * 8);
}

DEV void mma_bf16(const u16* As, const u16* Bs, int wr, int wc, int m, int quad, floatx4 acc[4][4]) {
  short8 af[4], bf[4];
#pragma unroll
  for (int t = 0; t < 4; ++t) af[t] = frag_ld(As, wr * 64 + t * 16 + m, quad);
#pragma unroll
  for (int t = 0; t < 4; ++t) bf[t] = frag_ld(Bs, wc * 64 + t * 16 + m, quad);
#pragma unroll
  for (int rt = 0; rt < 4; ++rt)
#pragma unroll
    for (int ct = 0; ct < 4; ++ct)
      acc[rt][ct] = __builtin_amdgcn_mfma_f32_16x16x32_bf16(af[rt], bf[ct], acc[rt][ct], 0, 0, 0);
}

DEV void mma_f16(const u16* As, const u16* Bs, int wr, int wc, int m, int quad, floatx4 acc[4][4]) {
  union { short8 s; half8 h; } af[4], bf[4];
#pragma unroll
  for (int t = 0; t < 4; ++t) af[t].s = frag_ld(As, wr * 64 + t * 16 + m, quad);
#pragma unroll
  for (int t = 0; t < 4; ++t) bf[t].s = frag_ld(Bs, wc * 64 + t * 16 + m, quad);
#pragma unroll
  for (int rt = 0; rt < 4; ++rt)
#pragma unroll
    for (int ct = 0; ct < 4; ++ct)
      acc[rt][ct] = __builtin_amdgcn_mfma_f32_16x16x32_f16(af[rt].h, bf[ct].h, acc[rt][ct], 0, 0, 0);
}

// Dekker 3-pass: hh + hl + lh (bf16 operands, ~2^-16 effective)
DEV void mma_split(const u16* AsH, const u16* AsL, const u16* BsH, const u16* BsL,
                   int wr, int wc, int m, int quad, floatx4 acc[4][4]) {
  short8 ah[4], al[4], bh[4], bl[4];
#pragma unroll
  for (int t = 0; t < 4; ++t) {
    ah[t] = frag_ld(AsH, wr * 64 + t * 16 + m, quad);
    al[t] = frag_ld(AsL, wr * 64 + t * 16 + m, quad);
    bh[t] = frag_ld(BsH, wc * 64 + t * 16 + m, quad);
    bl[t] = frag_ld(BsL, wc * 64 + t * 16 + m, quad);
  }
#pragma unroll
  for (int rt = 0; rt < 4; ++rt)
#pragma unroll
    for (int ct = 0; ct < 4; ++ct) {
      acc[rt][ct] = __builtin_amdgcn_mfma_f32_16x16x32_bf16(ah[rt], bh[ct], acc[rt][ct], 0, 0, 0);
      acc[rt][ct] = __builtin_amdgcn_mfma_f32_16x16x32_bf16(ah[rt], bl[ct], acc[rt][ct], 0, 0, 0);
      acc[rt][ct] = __builtin_amdgcn_mfma_f32_16x16x32_bf16(al[rt], bh[ct], acc[rt][ct], 0, 0, 0);
    }
}

DEV void acc_zero(floatx4 acc[4][4]) {
  floatx4 z = {0.f, 0.f, 0.f, 0.f};
#pragma unroll
  for (int i = 0; i < 4; ++i)
#pragma unroll
    for (int j = 0; j < 4; ++j) acc[i][j] = z;
}

// ---------------- all 5 projections, one launch ----------------
// z: 0=q_bpe(bf16) 1=k_bpe(bf16) 2=V->VT(bf16) 3=q_word(Dekker->transposed h/l)
//    4=k_word(Dekker->transposed h/l)
struct PAll {
  const float* X[5]; const float* W[5]; const float* bias[5];
  float scale[5]; u16* dh[5]; u16* dl[5]; int T[5]; int md[5];  // 0 plain,1 VT,2 word-split-T
};

__global__ __launch_bounds__(256) void proj_all_kernel(PAll a) {
  const int z = blockIdx.z;
  const int T = a.T[z];
  if ((int)blockIdx.y >= (T >> 5)) return;
  __shared__ __align__(16) u16 AsH[4096], AsL[4096], BsH[4096], BsL[4096];
  const int tid = threadIdx.x;
  const int lane = tid & 63, wv = tid >> 6, wr = wv >> 1, wc = wv & 1;
  const int m = lane & 15, quad = lane >> 4;
  const float* A = a.X[z] + (size_t)blockIdx.y * 128 * 1024;
  const float* B = a.W[z] + (size_t)blockIdx.x * 128 * 1024;
  const int md = a.md[z];
  floatx4 acc[4][4];
  acc_zero(acc);
  for (int k0 = 0; k0 < 1024; k0 += 32) {
    __syncthreads();
    if (md == 2) {
      stage_f32_split(A + k0, 1024, AsH, AsL, tid);
      stage_f32_split(B + k0, 1024, BsH, BsL, tid);
    } else {
      stage_f32_bf(A + k0, 1024, AsH, tid);
      stage_f32_bf(B + k0, 1024, BsH, tid);
    }
    __syncthreads();
    if (md == 2) mma_split(AsH, AsL, BsH, BsL, wr, wc, m, quad, acc);
    else         mma_bf16(AsH, BsH, wr, wc, m, quad, acc);
  }
  const float scale = a.scale[z];
  const float* bias = a.bias[z];
  u16* dh = a.dh[z];
  u16* dl = a.dl[z];
  const int row0 = blockIdx.y * 128 + wr * 64 + quad * 4;
  const int col0 = blockIdx.x * 128 + wc * 64 + m;
#pragma unroll
  for (int rt = 0; rt < 4; ++rt)
#pragma unroll
    for (int ct = 0; ct < 4; ++ct) {
      int col = col0 + ct * 16;
      float bi = bias[col];
      int h = col >> 6, d = col & 63;
#pragma unroll
      for (int rg = 0; rg < 4; ++rg) {
        int row = row0 + rt * 16 + rg;
        int t = row >> 2, bb = row & 3, n = bb * 16 + h;
        float val = (acc[rt][ct][rg] + bi) * scale;
        if (md == 1) {
          dh[((size_t)n * 64 + d) * 1024 + t] = f2bf(val);        // VT[n][d][t]
        } else if (md == 2) {
          size_t idx = ((size_t)n * 64 + d) * 512 + t;            // [n][d][w] transposed
          u16 hh = f2bf(val);
          dh[idx] = hh;
          dl[idx] = f2bf(val - bf2f(hh));
        } else {
          dh[((size_t)n * T + t) * 64 + d] = f2bf(val);           // [n][t][d]
        }
      }
    }
}

// ---------------- M -> Mh,Ml (bf16 Dekker) + Mf (fp16) ----------------
__global__ __launch_bounds__(256) void msplit_kernel(const float* __restrict__ M,
                                                     u16* __restrict__ Mh, u16* __restrict__ Ml,
                                                     u16* __restrict__ Mf) {
  int i = blockIdx.x * 256 + threadIdx.x;
  float f = M[i];
  u16 h = f2bf(f);
  Mh[i] = h;
  Ml[i] = f2bf(f - bf2f(h));
  Mf[i] = f2h_bits(f);
}

// ---------------- rel tables ----------------
__global__ __launch_bounds__(256) void rel_bpe_kernel(const u16* __restrict__ q,
                                                      const float* __restrict__ relk,
                                                      float* __restrict__ R) {
  int nt = blockIdx.x * 256 + threadIdx.x;
  float qv[64];
#pragma unroll
  for (int c = 0; c < 8; ++c) {
    union { short8 s; u16 u[8]; } uh; uh.s = *(const short8*)(q + (size_t)nt * 64 + c * 8);
#pragma unroll
    for (int j = 0; j < 8; ++j) qv[c * 8 + j] = bf2f(uh.u[j]);
  }
  for (int r = 0; r < 33; ++r) {
    const float* krow = relk + r * 64;
    float s = 0.f;
#pragma unroll
    for (int d = 0; d < 64; ++d) s += qv[d] * krow[d];
    R[(size_t)nt * 33 + r] = s;
  }
}

// q_word transposed hi/lo [n][d][w]
__global__ __launch_bounds__(256) void rel_word_kernel(const u16* __restrict__ qh, const u16* __restrict__ ql,
                                                       const float* __restrict__ relk,
                                                       float* __restrict__ R) {
  int nt = blockIdx.x * 256 + threadIdx.x;
  int n = nt >> 9, w = nt & 511;
  float qv[64];
#pragma unroll
  for (int d = 0; d < 64; ++d) {
    size_t idx = ((size_t)n * 64 + d) * 512 + w;
    qv[d] = bf2f(qh[idx]) + bf2f(ql[idx]);
  }
  for (int r = 0; r < 33; ++r) {
    const float* krow = relk + r * 64;
    float s = 0.f;
#pragma unroll
    for (int d = 0; d < 64; ++d) s += qv[d] * krow[d];
    R[(size_t)nt * 33 + r] = s;
  }
}

// ---------------- RelT build: RelT[nl][s][w] = R_word[n][w][clip(s-w)+16] (fp16) ----
__global__ __launch_bounds__(256) void relmat_kernel(const float* __restrict__ Rw,
                                                     u16* __restrict__ RelT, int n0) {
  int idx = blockIdx.x * 256 + threadIdx.x;
  int w = idx & 511, s = (idx >> 9) & 511, nl = idx >> 18;
  int n = n0 + nl;
  int d = s - w; d = d < -16 ? -16 : (d > 16 ? 16 : d); d += 16;
  RelT[idx] = f2h_bits(Rw[((size_t)n * 512 + w) * 33 + d]);
}

// ---------------- MQ/MK: [1024,64] = M[1024,512] x {Q,K}^T, Dekker 3-pass ------
__global__ __launch_bounds__(256) void mqk_kernel(const u16* __restrict__ Mh, const u16* __restrict__ Ml,
                                                  const u16* __restrict__ qwTh, const u16* __restrict__ qwTl,
                                                  const u16* __restrict__ kwTh, const u16* __restrict__ kwTl,
                                                  float* __restrict__ MQ, float* __restrict__ MK, int n0) {
  __shared__ __align__(16) u16 AsH[4096], AsL[4096], BsH[4096], BsL[4096];
  const int tid = threadIdx.x, nl = blockIdx.y, n = n0 + nl, b = n >> 4;
  const int lane = tid & 63, wv = tid >> 6, wr = wv >> 1, wc = wv & 1;
  const int m = lane & 15, quad = lane >> 4;
  const size_t ma = ((size_t)b * 1024 + blockIdx.x * 128) * 512;
  const u16* Qh = qwTh + (size_t)n * 32768;  // 64 rows (d), ld 512
  const u16* Ql = qwTl + (size_t)n * 32768;
  const u16* Kh = kwTh + (size_t)n * 32768;
  const u16* Kl = kwTl + (size_t)n * 32768;
  floatx4 acc[4][4];
  acc_zero(acc);
  for (int k0 = 0; k0 < 512; k0 += 32) {
    __syncthreads();
    stage_u16(Mh + ma + k0, 512, AsH, tid);
    stage_u16(Ml + ma + k0, 512, AsL, tid);
    stage_u16_half(Qh + k0, 512, BsH, tid, 0);  // B rows 0..63  = Q d
    stage_u16_half(Kh + k0, 512, BsH, tid, 1);  // B rows 64..127 = K d
    stage_u16_half(Ql + k0, 512, BsL, tid, 0);
    stage_u16_half(Kl + k0, 512, BsL, tid, 1);
    __syncthreads();
    mma_split(AsH, AsL, BsH, BsL, wr, wc, m, quad, acc);
  }
  float* dst = wc ? MK : MQ;
  const int row0 = blockIdx.x * 128 + wr * 64 + quad * 4;
#pragma unroll
  for (int rt = 0; rt < 4; ++rt)
#pragma unroll
    for (int ct = 0; ct < 4; ++ct) {
      int d = (ct * 16 + m) & 63;
#pragma unroll
      for (int rg = 0; rg < 4; ++rg) {
        int row = row0 + rt * 16 + rg;
        dst[((size_t)nl * 1024 + row) * 64 + d] = acc[rt][ct][rg];
      }
    }
}

// ------ stage1 (fp16): C1r[nl][q][s] = sum_w Mf[b][q][w] * RelT[nl][s][w] ------
__global__ __launch_bounds__(256) void stage1_kernel(const u16* __restrict__ Mf, const u16* __restrict__ RelT,
                                                     u16* __restrict__ C1r, int n0) {
  __shared__ __align__(16) u16 As[4096], Bs[4096];
  const int tid = threadIdx.x, nl = blockIdx.z, n = n0 + nl, b = n >> 4;
  const int lane = tid & 63, wv = tid >> 6, wr = wv >> 1, wc = wv & 1;
  const int m = lane & 15, quad = lane >> 4;
  const size_t ma = ((size_t)b * 1024 + blockIdx.y * 128) * 512;
  const size_t ra = ((size_t)nl * 512 + blockIdx.x * 128) * 512;
  floatx4 acc[4][4];
  acc_zero(acc);
  for (int k0 = 0; k0 < 512; k0 += 32) {
    __syncthreads();
    stage_u16(Mf + ma + k0, 512, As, tid);
    stage_u16(RelT + ra + k0, 512, Bs, tid);
    __syncthreads();
    mma_f16(As, Bs, wr, wc, m, quad, acc);
  }
  const int q0 = blockIdx.y * 128 + wr * 64 + quad * 4;
  const int s0 = blockIdx.x * 128 + wc * 64 + m;
#pragma unroll
  for (int rt = 0; rt < 4; ++rt)
#pragma unroll
    for (int ct = 0; ct < 4; ++ct) {
      int s = s0 + ct * 16;
#pragma unroll
      for (int rg = 0; rg < 4; ++rg) {
        int q = q0 + rt * 16 + rg;
        C1r[((size_t)nl * 1024 + q) * 512 + s] = f2h_bits(acc[rt][ct][rg]);
      }
    }
}

// ------ logits: qb.kb (bf16,K64) + MQ.MK^T (Dekker,K64) + C1r.Mf^T (fp16,K512) + rel --
__global__ __launch_bounds__(256) void logits_kernel(const u16* __restrict__ qb, const u16* __restrict__ kb,
                                                     const float* __restrict__ MQ, const float* __restrict__ MK,
                                                     const u16* __restrict__ C1r, const u16* __restrict__ Mf,
                                                     const float* __restrict__ Rb, float* __restrict__ L,
                                                     int n0) {
  __shared__ __align__(16) u16 AsH[4096], AsL[4096], BsH[4096], BsL[4096];
  const int tid = threadIdx.x, nl = blockIdx.z, n = n0 + nl, b = n >> 4;
  const int lane = tid & 63, wv = tid >> 6, wr = wv >> 1, wc = wv & 1;
  const int m = lane & 15, quad = lane >> 4;
  const size_t qa = ((size_t)n * 1024 + blockIdx.y * 128) * 64;
  const size_t ka = ((size_t)n * 1024 + blockIdx.x * 128) * 64;
  const size_t mqa = ((size_t)nl * 1024 + blockIdx.y * 128) * 64;
  const size_t mka = ((size_t)nl * 1024 + blockIdx.x * 128) * 64;
  const size_t ca = ((size_t)nl * 1024 + blockIdx.y * 128) * 512;
  const size_t ma = ((size_t)b * 1024 + blockIdx.x * 128) * 512;
  floatx4 acc[4][4];
  acc_zero(acc);
  for (int k0 = 0; k0 < 64; k0 += 32) {  // content QK^T bpe (bf16)
    __syncthreads();
    stage_u16(qb + qa + k0, 64, AsH, tid);
    stage_u16(kb + ka + k0, 64, BsH, tid);
    __syncthreads();
    mma_bf16(AsH, BsH, wr, wc, m, quad, acc);
  }
  for (int k0 = 0; k0 < 64; k0 += 32) {  // (MQ)(MK)^T fused content (Dekker)
    __syncthreads();
    stage_f32_split(MQ + mqa + k0, 64, AsH, AsL, tid);
    stage_f32_split(MK + mka + k0, 64, BsH, BsL, tid);
    __syncthreads();
    mma_split(AsH, AsL, BsH, BsL, wr, wc, m, quad, acc);
  }
  for (int k0 = 0; k0 < 512; k0 += 32) {  // M Rel M^T part 2: C1r @ Mf^T (fp16)
    __syncthreads();
    stage_u16(C1r + ca + k0, 512, AsH, tid);
    stage_u16(Mf + ma + k0, 512, BsH, tid);
    __syncthreads();
    mma_f16(AsH, BsH, wr, wc, m, quad, acc);
  }
  const int q0 = blockIdx.y * 128 + wr * 64 + quad * 4;
  const int k0c = blockIdx.x * 128 + wc * 64 + m;
#pragma unroll
  for (int rt = 0; rt < 4; ++rt)
#pragma unroll
    for (int ct = 0; ct < 4; ++ct) {
      int kc = k0c + ct * 16;
#pragma unroll
      for (int rg = 0; rg < 4; ++rg) {
        int q = q0 + rt * 16 + rg;
        int id = kc - q; id = id < -16 ? -16 : (id > 16 ? 16 : id); id += 16;
        float val = acc[rt][ct][rg] + Rb[((size_t)n * 1024 + q) * 33 + id];
        L[((size_t)nl * 1024 + q) * 1024 + kc] = val;
      }
    }
}

// ---------------- softmax + PV (online; fp32 logits in A-frag layout) ----------
__global__ __launch_bounds__(256) void softmax_pv_kernel(const float* __restrict__ L,
                                                         const u16* __restrict__ VT,
                                                         u16* __restrict__ AO, int n0) {
  __shared__ __align__(16) u16 Vs[4][2048];
  const int tid = threadIdx.x, lane = tid & 63, wv = tid >> 6;
  const int m = lane & 15, quad = lane >> 4;
  const int nl = blockIdx.y, n = n0 + nl, qt = blockIdx.x;
  const int qrow = qt * 64 + wv * 16 + m;
  const float* Lrow = L + ((size_t)nl * 1024 + qrow) * 1024;
  const u16* Vbase = VT + (size_t)n * 64 * 1024;
  float mi = -1e30f, li = 0.f;
  floatx4 O[4];
  floatx4 z = {0.f, 0.f, 0.f, 0.f};
#pragma unroll
  for (int dt = 0; dt < 4; ++dt) O[dt] = z;

  for (int kt = 0; kt < 8; ++kt) {
    __syncthreads();
#pragma unroll
    for (int ct = 0; ct < 4; ++ct) {
      int o = tid * 16;
      int r = o >> 6, c = (o >> 4) & 3, sc = c ^ ((r >> 1) & 3);
      __builtin_amdgcn_global_load_lds(GAS(Vbase + (size_t)r * 1024 + kt * 128 + ct * 32 + sc * 8),
                                       LAS((char*)Vs[ct] + o), 16, 0, 0);
    }
    __syncthreads();

    float vals[4][8];
#pragma unroll
    for (int ct = 0; ct < 4; ++ct) {
      const floatx4* p4 = (const floatx4*)(Lrow + kt * 128 + ct * 32 + quad * 8);
      floatx4 v0 = p4[0], v1 = p4[1];
#pragma unroll
      for (int j = 0; j < 4; ++j) { vals[ct][j] = v0[j]; vals[ct][4 + j] = v1[j]; }
    }
    float tmax = vals[0][0];
#pragma unroll
    for (int ct = 0; ct < 4; ++ct)
#pragma unroll
      for (int j = 0; j < 8; ++j) tmax = fmaxf(tmax, vals[ct][j]);
    tmax = fmaxf(tmax, __shfl_xor(tmax, 16));
    tmax = fmaxf(tmax, __shfl_xor(tmax, 32));
    float mnew = fmaxf(mi, tmax);
    float alpha = __expf(mi - mnew);
    float pv[4][8];
    float tsum = 0.f;
#pragma unroll
    for (int ct = 0; ct < 4; ++ct)
#pragma unroll
      for (int j = 0; j < 8; ++j) { pv[ct][j] = __expf(vals[ct][j] - mnew); tsum += pv[ct][j]; }
    tsum += __shfl_xor(tsum, 16);
    tsum += __shfl_xor(tsum, 32);
    li = li * alpha + tsum;
    mi = mnew;

    float ar[4];
#pragma unroll
    for (int rg = 0; rg < 4; ++rg) ar[rg] = __shfl(alpha, quad * 4 + rg);
#pragma unroll
    for (int dt = 0; dt < 4; ++dt)
#pragma unroll
      for (int rg = 0; rg < 4; ++rg) O[dt][rg] *= ar[rg];

    short8 pf[4];
#pragma unroll
    for (int ct = 0; ct < 4; ++ct) {
      union { short8 s; u16 us[8]; } up;
#pragma unroll
      for (int j = 0; j < 8; ++j) up.us[j] = f2bf(pv[ct][j]);
      pf[ct] = up.s;
    }
#pragma unroll
    for (int ct = 0; ct < 4; ++ct)
#pragma unroll
      for (int dt = 0; dt < 4; ++dt) {
        short8 vf = frag_ld(Vs[ct], dt * 16 + m, quad);
        O[dt] = __builtin_amdgcn_mfma_f32_16x16x32_bf16(pf[ct], vf, O[dt], 0, 0, 0);
      }
  }

  float linv = 1.f / li;
  float lr[4];
#pragma unroll
  for (int rg = 0; rg < 4; ++rg) lr[rg] = __shfl(linv, quad * 4 + rg);
  const int b = n >> 4, h = n & 15;
#pragma unroll
  for (int dt = 0; dt < 4; ++dt)
#pragma unroll
    for (int rg = 0; rg < 4; ++rg) {
      int q = qt * 64 + wv * 16 + quad * 4 + rg;
      float ov = O[dt][rg] * lr[rg];
      AO[((size_t)q * 4 + b) * 1024 + h * 64 + dt * 16 + m] = f2bf(ov);
    }
}

// ---------------- output projection: out = AO @ Wo^T + bo  (fp32 out) ----------
__global__ __launch_bounds__(256) void outproj_kernel(const u16* __restrict__ AO, const float* __restrict__ Wo,
                                                      const float* __restrict__ bo, float* __restrict__ out) {
  __shared__ __align__(16) u16 As[4096], Bs[4096];
  const int tid = threadIdx.x;
  const int lane = tid & 63, wv = tid >> 6, wr = wv >> 1, wc = wv & 1;
  const int m = lane & 15, quad = lane >> 4;
  const u16* A = AO + (size_t)blockIdx.y * 128 * 1024;
  const float* B = Wo + (size_t)blockIdx.x * 128 * 1024;
  floatx4 acc[4][4];
  acc_zero(acc);
  for (int k0 = 0; k0 < 1024; k0 += 32) {
    __syncthreads();
    stage_u16(A + k0, 1024, As, tid);
    stage_f32_bf(B + k0, 1024, Bs, tid);
    __syncthreads();
    mma_bf16(As, Bs, wr, wc, m, quad, acc);
  }
  const int r0 = blockIdx.y * 128 + wr * 64 + quad * 4;
  const int c0 = blockIdx.x * 128 + wc * 64 + m;
#pragma unroll
  for (int rt = 0; rt < 4; ++rt)
#pragma unroll
    for (int ct = 0; ct < 4; ++ct) {
      int col = c0 + ct * 16;
      float bi = bo[col];
#pragma unroll
      for (int rg = 0; rg < 4; ++rg) {
        int row = r0 + rt * 16 + rg;
        out[(size_t)row * 1024 + col] = acc[rt][ct][rg] + bi;
      }
    }
}

extern "C" void kernel_launch(void* const* d_in, const int* in_sizes, int n_in,
                              void* d_out, int out_size, void* d_ws, size_t ws_size,
                              hipStream_t stream) {
  const float* query_bpe = (const float*)d_in[0];
  const float* query_word = (const float*)d_in[1];
  const float* mapping = (const float*)d_in[2];
  const float* Wq_bpe = (const float*)d_in[3];
  const float* bq_bpe = (const float*)d_in[4];
  const float* Wk_bpe = (const float*)d_in[5];
  const float* bk_bpe = (const float*)d_in[6];
  const float* Wq_word = (const float*)d_in[7];
  const float* bq_word = (const float*)d_in[8];
  const float* Wk_word = (const float*)d_in[9];
  const float* bk_word = (const float*)d_in[10];
  const float* Wv = (const float*)d_in[11];
  const float* bv = (const float*)d_in[12];
  const float* Wo = (const float*)d_in[13];
  const float* bo = (const float*)d_in[14];
  const float* relk = (const float*)d_in[15];

  char* ws = (char*)d_ws;
  size_t off = 0;
  u16* q_bpe = (u16*)(ws + off); off += 8388608;   // [64][1024][64] bf16
  u16* k_bpe = (u16*)(ws + off); off += 8388608;
  u16* VTb   = (u16*)(ws + off); off += 8388608;   // [64][64][1024] bf16
  u16* qwT_h = (u16*)(ws + off); off += 4194304;   // [64][64][512] bf16 hi (transposed)
  u16* qwT_l = (u16*)(ws + off); off += 4194304;
  u16* kwT_h = (u16*)(ws + off); off += 4194304;
  u16* kwT_l = (u16*)(ws + off); off += 4194304;
  u16* M_h   = (u16*)(ws + off); off += 4194304;   // [4][1024][512] bf16
  u16* M_l   = (u16*)(ws + off); off += 4194304;
  u16* M_f   = (u16*)(ws + off); off += 4194304;   // fp16
  float* R_word = (float*)(ws + off); off += 4325376;  // [64][512][33]
  float* R_bpe  = (float*)(ws + off); off += 8650752;  // [64][1024][33]
  u16* AO    = (u16*)(ws + off); off += 8388608;   // [4096][1024] bf16
  const size_t fixed_end = off;                    // ~77.5 MB

  // per chunk: RelT fp16 0.5MB + C1r fp16 1MB + L fp32 4MB + MQ 0.25MB + MK 0.25MB
  const size_t per_nc = 6291456;  // 6 MB
  int NC = 1;
  for (int c = 64; c >= 1; c >>= 1) {
    if (fixed_end + (size_t)c * per_nc <= ws_size) { NC = c; break; }
  }
  char* vb = ws + fixed_end;
  u16* RelT  = (u16*)(vb);
  u16* C1r   = (u16*)(vb + (size_t)NC * 524288);
  float* L_c = (float*)(vb + (size_t)NC * 1572864);
  float* MQ  = (float*)(vb + (size_t)NC * 5767168);
  float* MK  = (float*)(vb + (size_t)NC * 6029312);

  PAll pa = {};
  pa.X[0] = query_bpe;  pa.W[0] = Wq_bpe;  pa.bias[0] = bq_bpe;  pa.scale[0] = 0.125f; pa.dh[0] = q_bpe; pa.T[0] = 1024; pa.md[0] = 0;
  pa.X[1] = query_bpe;  pa.W[1] = Wk_bpe;  pa.bias[1] = bk_bpe;  pa.scale[1] = 1.0f;   pa.dh[1] = k_bpe; pa.T[1] = 1024; pa.md[1] = 0;
  pa.X[2] = query_bpe;  pa.W[2] = Wv;      pa.bias[2] = bv;      pa.scale[2] = 1.0f;   pa.dh[2] = VTb;   pa.T[2] = 1024; pa.md[2] = 1;
  pa.X[3] = query_word; pa.W[3] = Wq_word; pa.bias[3] = bq_word; pa.scale[3] = 0.125f; pa.dh[3] = qwT_h; pa.dl[3] = qwT_l; pa.T[3] = 512; pa.md[3] = 2;
  pa.X[4] = query_word; pa.W[4] = Wk_word; pa.bias[4] = bk_word; pa.scale[4] = 1.0f;   pa.dh[4] = kwT_h; pa.dl[4] = kwT_l; pa.T[4] = 512; pa.md[4] = 2;
  proj_all_kernel<<<dim3(8, 32, 5), 256, 0, stream>>>(pa);

  msplit_kernel<<<dim3(4 * 1024 * 512 / 256), 256, 0, stream>>>(mapping, M_h, M_l, M_f);

  rel_bpe_kernel<<<dim3(64 * 1024 / 256), 256, 0, stream>>>(q_bpe, relk, R_bpe);
  rel_word_kernel<<<dim3(64 * 512 / 256), 256, 0, stream>>>(qwT_h, qwT_l, relk, R_word);

  for (int n0 = 0; n0 < 64; n0 += NC) {
    relmat_kernel<<<dim3(NC * 1024), 256, 0, stream>>>(R_word, RelT, n0);
    mqk_kernel<<<dim3(8, NC), 256, 0, stream>>>(M_h, M_l, qwT_h, qwT_l, kwT_h, kwT_l, MQ, MK, n0);
    stage1_kernel<<<dim3(4, 8, NC), 256, 0, stream>>>(M_f, RelT, C1r, n0);
    logits_kernel<<<dim3(8, 8, NC), 256, 0, stream>>>(q_bpe, k_bpe, MQ, MK, C1r, M_f, R_bpe, L_c, n0);
    softmax_pv_kernel<<<dim3(16, NC), 256, 0, stream>>>(L_c, VTb, AO, n0);
  }

  outproj_kernel<<<dim3(8, 32), 256, 0, stream>>>(AO, Wo, bo, (float*)d_out);
}

// Round 9
// 765.622 us; speedup vs baseline: 1.4026x; 1.1906x over previous
//
#include <hip/hip_runtime.h>

// RelativeBPEWORDFusionMultiheadAttention on MI355X (gfx950). FP32 in/out.
// Factorization: fused = (MQ)(MK)^T + M·Rel·M^T (content Dekker-bf16, Rel fp16).
// Round 9: all fp32 inputs pre-converted once (bf16 / Dekker hi-lo pairs), so
// every GEMM stages with pure async global_load_lds (no VALU convert, half the
// tile bytes). Logits buffer fp16 (halves the L round-trip). Prep buffers are
// transient and overlap the per-chunk loop region (stream-serialized).

#define DEV __device__ __forceinline__
#define GAS(x) ((const __attribute__((address_space(1))) unsigned*)(x))
#define LAS(x) ((__attribute__((address_space(3))) unsigned*)(x))

typedef unsigned short u16;
typedef __attribute__((ext_vector_type(8))) short short8;
typedef __attribute__((ext_vector_type(8))) _Float16 half8;
typedef __attribute__((ext_vector_type(4))) float floatx4;

DEV float bf2f(u16 u) { union { unsigned u; float f; } v; v.u = ((unsigned)u) << 16; return v.f; }
DEV u16 f2bf(float f) {
  union { float f; unsigned u; } v; v.f = f;
  unsigned r = v.u + 0x7FFFu + ((v.u >> 16) & 1u);  // RNE
  return (u16)(r >> 16);
}
DEV u16 f2h_bits(float f) { union { _Float16 h; u16 u; } v; v.h = (_Float16)f; return v.u; }

// ---- LDS tile [128][32] u16, 16B-chunk XOR swizzle (source-side permute) ----
DEV void stage_u16(const u16* g, int ld, u16* lds, int tid) {
#pragma unroll
  for (int p = 0; p < 2; ++p) {
    int o = (p * 256 + tid) * 16;
    int r = o >> 6, c = (o >> 4) & 3, sc = c ^ ((r >> 1) & 3);
    __builtin_amdgcn_global_load_lds(GAS(g + (size_t)r * ld + sc * 8),
                                     LAS((char*)lds + o), 16, 0, 0);
  }
}

DEV void stage_u16_half(const u16* g, int ld, u16* lds, int tid, int p) {
  int o = (p * 256 + tid) * 16;
  int r = o >> 6, c = (o >> 4) & 3, sc = c ^ ((r >> 1) & 3);
  __builtin_amdgcn_global_load_lds(GAS(g + (size_t)(r - p * 64) * ld + sc * 8),
                                   LAS((char*)lds + o), 16, 0, 0);
}

DEV void stage_f32_bf(const float* g, int ld, u16* lds, int tid) {
#pragma unroll
  for (int p = 0; p < 2; ++p) {
    int o = (p * 256 + tid) * 16;
    int r = o >> 6, c = (o >> 4) & 3, sc = c ^ ((r >> 1) & 3);
    const float* src = g + (size_t)r * ld + sc * 8;
    union { short8 s; u16 u[8]; } oh;
#pragma unroll
    for (int j = 0; j < 8; ++j) oh.u[j] = f2bf(src[j]);
    *(short8*)((char*)lds + o) = oh.s;
  }
}

DEV void stage_f32_split(const float* g, int ld, u16* ldsh, u16* ldsl, int tid) {
#pragma unroll
  for (int p = 0; p < 2; ++p) {
    int o = (p * 256 + tid) * 16;
    int r = o >> 6, c = (o >> 4) & 3, sc = c ^ ((r >> 1) & 3);
    const float* src = g + (size_t)r * ld + sc * 8;
    union { short8 s; u16 u[8]; } oh, ol;
#pragma unroll
    for (int j = 0; j < 8; ++j) {
      float f = src[j];
      u16 h = f2bf(f);
      oh.u[j] = h;
      ol.u[j] = f2bf(f - bf2f(h));
    }
    *(short8*)((char*)ldsh + o) = oh.s;
    *(short8*)((char*)ldsl + o) = ol.s;
  }
}

DEV short8 frag_ld(const u16* lds, int row, int quad) {
  int c = quad ^ ((row >> 1) & 3);
  return *(const short8*)(lds + row * 32 + c * 8);
}

DEV void mma_bf16(const u16* As, const u16* Bs, int wr, int wc, int m, int quad, floatx4 acc[4][4]) {
  short8 af[4], bf[4];
#pragma unroll
  for (int t = 0; t < 4; ++t) af[t] = frag_ld(As, wr * 64 + t * 16 + m, quad);
#pragma unroll
  for (int t = 0; t < 4; ++t) bf[t] = frag_ld(Bs, wc * 64 + t * 16 + m, quad);
#pragma unroll
  for (int rt = 0; rt < 4; ++rt)
#pragma unroll
    for (int ct = 0; ct < 4; ++ct)
      acc[rt][ct] = __builtin_amdgcn_mfma_f32_16x16x32_bf16(af[rt], bf[ct], acc[rt][ct], 0, 0, 0);
}

DEV void mma_f16(const u16* As, const u16* Bs, int wr, int wc, int m, int quad, floatx4 acc[4][4]) {
  union { short8 s; half8 h; } af[4], bf[4];
#pragma unroll
  for (int t = 0; t < 4; ++t) af[t].s = frag_ld(As, wr * 64 + t * 16 + m, quad);
#pragma unroll
  for (int t = 0; t < 4; ++t) bf[t].s = frag_ld(Bs, wc * 64 + t * 16 + m, quad);
#pragma unroll
  for (int rt = 0; rt < 4; ++rt)
#pragma unroll
    for (int ct = 0; ct < 4; ++ct)
      acc[rt][ct] = __builtin_amdgcn_mfma_f32_16x16x32_f16(af[rt].h, bf[ct].h, acc[rt][ct], 0, 0, 0);
}

// Dekker 3-pass: hh + hl + lh (bf16 operands, ~2^-16 effective)
DEV void mma_split(const u16* AsH, const u16* AsL, const u16* BsH, const u16* BsL,
                   int wr, int wc, int m, int quad, floatx4 acc[4][4]) {
  short8 ah[4], al[4], bh[4], bl[4];
#pragma unroll
  for (int t = 0; t < 4; ++t) {
    ah[t] = frag_ld(AsH, wr * 64 + t * 16 + m, quad);
    al[t] = frag_ld(AsL, wr * 64 + t * 16 + m, quad);
    bh[t] = frag_ld(BsH, wc * 64 + t * 16 + m, quad);
    bl[t] = frag_ld(BsL, wc * 64 + t * 16 + m, quad);
  }
#pragma unroll
  for (int rt = 0; rt < 4; ++rt)
#pragma unroll
    for (int ct = 0; ct < 4; ++ct) {
      acc[rt][ct] = __builtin_amdgcn_mfma_f32_16x16x32_bf16(ah[rt], bh[ct], acc[rt][ct], 0, 0, 0);
      acc[rt][ct] = __builtin_amdgcn_mfma_f32_16x16x32_bf16(ah[rt], bl[ct], acc[rt][ct], 0, 0, 0);
      acc[rt][ct] = __builtin_amdgcn_mfma_f32_16x16x32_bf16(al[rt], bh[ct], acc[rt][ct], 0, 0, 0);
    }
}

DEV void acc_zero(floatx4 acc[4][4]) {
  floatx4 z = {0.f, 0.f, 0.f, 0.f};
#pragma unroll
  for (int i = 0; i < 4; ++i)
#pragma unroll
    for (int j = 0; j < 4; ++j) acc[i][j] = z;
}

// ---------------- input pre-conversion ----------------
struct CvtB { const float* src[5]; u16* dst[5]; int n8[5]; };
__global__ __launch_bounds__(256) void cvt_bf_kernel(CvtB a) {
  int z = blockIdx.z;
  int i = blockIdx.x * 256 + threadIdx.x;
  if (i >= a.n8[z]) return;
  const float* s = a.src[z] + (size_t)i * 8;
  union { short8 v; u16 u[8]; } o;
#pragma unroll
  for (int j = 0; j < 8; ++j) o.u[j] = f2bf(s[j]);
  *(short8*)(a.dst[z] + (size_t)i * 8) = o.v;
}

struct CvtS { const float* src[3]; u16* dh[3]; u16* dl[3]; int n8[3]; };
__global__ __launch_bounds__(256) void cvt_split_kernel(CvtS a) {
  int z = blockIdx.z;
  int i = blockIdx.x * 256 + threadIdx.x;
  if (i >= a.n8[z]) return;
  const float* s = a.src[z] + (size_t)i * 8;
  union { short8 v; u16 u[8]; } oh, ol;
#pragma unroll
  for (int j = 0; j < 8; ++j) {
    float f = s[j];
    u16 h = f2bf(f);
    oh.u[j] = h;
    ol.u[j] = f2bf(f - bf2f(h));
  }
  *(short8*)(a.dh[z] + (size_t)i * 8) = oh.v;
  *(short8*)(a.dl[z] + (size_t)i * 8) = ol.v;
}

// ---------------- all 5 projections, one launch ----------------
// z: 0=q_bpe(bf16) 1=k_bpe(bf16) 2=V->VT(bf16) 3=q_word(Dekker->transposed h/l)
//    4=k_word(Dekker->transposed h/l)
struct PAll {
  const float* Xf[5]; const float* Wf[5];
  const u16* Xh[5]; const u16* Xl[5]; const u16* Wh[5]; const u16* Wl[5];
  const float* bias[5]; float scale[5];
  u16* dh[5]; u16* dl[5]; int T[5]; int md[5]; int prep;
};

__global__ __launch_bounds__(256) void proj_all_kernel(PAll a) {
  const int z = blockIdx.z;
  const int T = a.T[z];
  if ((int)blockIdx.y >= (T >> 5)) return;
  __shared__ __align__(16) u16 AsH[4096], AsL[4096], BsH[4096], BsL[4096];
  const int tid = threadIdx.x;
  const int lane = tid & 63, wv = tid >> 6, wr = wv >> 1, wc = wv & 1;
  const int m = lane & 15, quad = lane >> 4;
  const int md = a.md[z], prep = a.prep;
  const size_t arow = (size_t)blockIdx.y * 128 * 1024;
  const size_t brow = (size_t)blockIdx.x * 128 * 1024;
  floatx4 acc[4][4];
  acc_zero(acc);
  for (int k0 = 0; k0 < 1024; k0 += 32) {
    __syncthreads();
    if (md == 2) {
      if (prep) {
        stage_u16(a.Xh[z] + arow + k0, 1024, AsH, tid);
        stage_u16(a.Xl[z] + arow + k0, 1024, AsL, tid);
        stage_u16(a.Wh[z] + brow + k0, 1024, BsH, tid);
        stage_u16(a.Wl[z] + brow + k0, 1024, BsL, tid);
      } else {
        stage_f32_split(a.Xf[z] + arow + k0, 1024, AsH, AsL, tid);
        stage_f32_split(a.Wf[z] + brow + k0, 1024, BsH, BsL, tid);
      }
    } else {
      if (prep) {
        stage_u16(a.Xh[z] + arow + k0, 1024, AsH, tid);
        stage_u16(a.Wh[z] + brow + k0, 1024, BsH, tid);
      } else {
        stage_f32_bf(a.Xf[z] + arow + k0, 1024, AsH, tid);
        stage_f32_bf(a.Wf[z] + brow + k0, 1024, BsH, tid);
      }
    }
    __syncthreads();
    if (md == 2) mma_split(AsH, AsL, BsH, BsL, wr, wc, m, quad, acc);
    else         mma_bf16(AsH, BsH, wr, wc, m, quad, acc);
  }
  const float scale = a.scale[z];
  const float* bias = a.bias[z];
  u16* dh = a.dh[z];
  u16* dl = a.dl[z];
  const int row0 = blockIdx.y * 128 + wr * 64 + quad * 4;
  const int col0 = blockIdx.x * 128 + wc * 64 + m;
#pragma unroll
  for (int rt = 0; rt < 4; ++rt)
#pragma unroll
    for (int ct = 0; ct < 4; ++ct) {
      int col = col0 + ct * 16;
      float bi = bias[col];
      int h = col >> 6, d = col & 63;
#pragma unroll
      for (int rg = 0; rg < 4; ++rg) {
        int row = row0 + rt * 16 + rg;
        int t = row >> 2, bb = row & 3, n = bb * 16 + h;
        float val = (acc[rt][ct][rg] + bi) * scale;
        if (md == 1) {
          dh[((size_t)n * 64 + d) * 1024 + t] = f2bf(val);        // VT[n][d][t]
        } else if (md == 2) {
          size_t idx = ((size_t)n * 64 + d) * 512 + t;            // [n][d][w] transposed
          u16 hh = f2bf(val);
          dh[idx] = hh;
          dl[idx] = f2bf(val - bf2f(hh));
        } else {
          dh[((size_t)n * T + t) * 64 + d] = f2bf(val);           // [n][t][d]
        }
      }
    }
}

// ---------------- M -> Mh,Ml (bf16 Dekker) + Mf (fp16) ----------------
__global__ __launch_bounds__(256) void msplit_kernel(const float* __restrict__ M,
                                                     u16* __restrict__ Mh, u16* __restrict__ Ml,
                                                     u16* __restrict__ Mf) {
  int i = blockIdx.x * 256 + threadIdx.x;
  float f = M[i];
  u16 h = f2bf(f);
  Mh[i] = h;
  Ml[i] = f2bf(f - bf2f(h));
  Mf[i] = f2h_bits(f);
}

// ---------------- rel tables ----------------
__global__ __launch_bounds__(256) void rel_bpe_kernel(const u16* __restrict__ q,
                                                      const float* __restrict__ relk,
                                                      float* __restrict__ R) {
  int nt = blockIdx.x * 256 + threadIdx.x;
  float qv[64];
#pragma unroll
  for (int c = 0; c < 8; ++c) {
    union { short8 s; u16 u[8]; } uh; uh.s = *(const short8*)(q + (size_t)nt * 64 + c * 8);
#pragma unroll
    for (int j = 0; j < 8; ++j) qv[c * 8 + j] = bf2f(uh.u[j]);
  }
  for (int r = 0; r < 33; ++r) {
    const float* krow = relk + r * 64;
    float s = 0.f;
#pragma unroll
    for (int d = 0; d < 64; ++d) s += qv[d] * krow[d];
    R[(size_t)nt * 33 + r] = s;
  }
}

__global__ __launch_bounds__(256) void rel_word_kernel(const u16* __restrict__ qh, const u16* __restrict__ ql,
                                                       const float* __restrict__ relk,
                                                       float* __restrict__ R) {
  int nt = blockIdx.x * 256 + threadIdx.x;
  int n = nt >> 9, w = nt & 511;
  float qv[64];
#pragma unroll
  for (int d = 0; d < 64; ++d) {
    size_t idx = ((size_t)n * 64 + d) * 512 + w;
    qv[d] = bf2f(qh[idx]) + bf2f(ql[idx]);
  }
  for (int r = 0; r < 33; ++r) {
    const float* krow = relk + r * 64;
    float s = 0.f;
#pragma unroll
    for (int d = 0; d < 64; ++d) s += qv[d] * krow[d];
    R[(size_t)nt * 33 + r] = s;
  }
}

// ---------------- RelT build: RelT[nl][s][w] = R_word[n][w][clip(s-w)+16] (fp16) ----
__global__ __launch_bounds__(256) void relmat_kernel(const float* __restrict__ Rw,
                                                     u16* __restrict__ RelT, int n0) {
  int idx = blockIdx.x * 256 + threadIdx.x;
  int w = idx & 511, s = (idx >> 9) & 511, nl = idx >> 18;
  int n = n0 + nl;
  int d = s - w; d = d < -16 ? -16 : (d > 16 ? 16 : d); d += 16;
  RelT[idx] = f2h_bits(Rw[((size_t)n * 512 + w) * 33 + d]);
}

// ---------------- MQ/MK: [1024,64] = M[1024,512] x {Q,K}^T, Dekker 3-pass ------
__global__ __launch_bounds__(256) void mqk_kernel(const u16* __restrict__ Mh, const u16* __restrict__ Ml,
                                                  const u16* __restrict__ qwTh, const u16* __restrict__ qwTl,
                                                  const u16* __restrict__ kwTh, const u16* __restrict__ kwTl,
                                                  float* __restrict__ MQ, float* __restrict__ MK, int n0) {
  __shared__ __align__(16) u16 AsH[4096], AsL[4096], BsH[4096], BsL[4096];
  const int tid = threadIdx.x, nl = blockIdx.y, n = n0 + nl, b = n >> 4;
  const int lane = tid & 63, wv = tid >> 6, wr = wv >> 1, wc = wv & 1;
  const int m = lane & 15, quad = lane >> 4;
  const size_t ma = ((size_t)b * 1024 + blockIdx.x * 128) * 512;
  const u16* Qh = qwTh + (size_t)n * 32768;
  const u16* Ql = qwTl + (size_t)n * 32768;
  const u16* Kh = kwTh + (size_t)n * 32768;
  const u16* Kl = kwTl + (size_t)n * 32768;
  floatx4 acc[4][4];
  acc_zero(acc);
  for (int k0 = 0; k0 < 512; k0 += 32) {
    __syncthreads();
    stage_u16(Mh + ma + k0, 512, AsH, tid);
    stage_u16(Ml + ma + k0, 512, AsL, tid);
    stage_u16_half(Qh + k0, 512, BsH, tid, 0);
    stage_u16_half(Kh + k0, 512, BsH, tid, 1);
    stage_u16_half(Ql + k0, 512, BsL, tid, 0);
    stage_u16_half(Kl + k0, 512, BsL, tid, 1);
    __syncthreads();
    mma_split(AsH, AsL, BsH, BsL, wr, wc, m, quad, acc);
  }
  float* dst = wc ? MK : MQ;
  const int row0 = blockIdx.x * 128 + wr * 64 + quad * 4;
#pragma unroll
  for (int rt = 0; rt < 4; ++rt)
#pragma unroll
    for (int ct = 0; ct < 4; ++ct) {
      int d = (ct * 16 + m) & 63;
#pragma unroll
      for (int rg = 0; rg < 4; ++rg) {
        int row = row0 + rt * 16 + rg;
        dst[((size_t)nl * 1024 + row) * 64 + d] = acc[rt][ct][rg];
      }
    }
}

// ------ stage1 (fp16): C1r[nl][q][s] = sum_w Mf[b][q][w] * RelT[nl][s][w] ------
__global__ __launch_bounds__(256) void stage1_kernel(const u16* __restrict__ Mf, const u16* __restrict__ RelT,
                                                     u16* __restrict__ C1r, int n0) {
  __shared__ __align__(16) u16 As[4096], Bs[4096];
  const int tid = threadIdx.x, nl = blockIdx.z, n = n0 + nl, b = n >> 4;
  const int lane = tid & 63, wv = tid >> 6, wr = wv >> 1, wc = wv & 1;
  const int m = lane & 15, quad = lane >> 4;
  const size_t ma = ((size_t)b * 1024 + blockIdx.y * 128) * 512;
  const size_t ra = ((size_t)nl * 512 + blockIdx.x * 128) * 512;
  floatx4 acc[4][4];
  acc_zero(acc);
  for (int k0 = 0; k0 < 512; k0 += 32) {
    __syncthreads();
    stage_u16(Mf + ma + k0, 512, As, tid);
    stage_u16(RelT + ra + k0, 512, Bs, tid);
    __syncthreads();
    mma_f16(As, Bs, wr, wc, m, quad, acc);
  }
  const int q0 = blockIdx.y * 128 + wr * 64 + quad * 4;
  const int s0 = blockIdx.x * 128 + wc * 64 + m;
#pragma unroll
  for (int rt = 0; rt < 4; ++rt)
#pragma unroll
    for (int ct = 0; ct < 4; ++ct) {
      int s = s0 + ct * 16;
#pragma unroll
      for (int rg = 0; rg < 4; ++rg) {
        int q = q0 + rt * 16 + rg;
        C1r[((size_t)nl * 1024 + q) * 512 + s] = f2h_bits(acc[rt][ct][rg]);
      }
    }
}

// ------ logits: qb.kb (bf16,K64) + MQ.MK^T (Dekker,K64) + C1r.Mf^T (fp16,K512) + rel --
// L stored fp16.
__global__ __launch_bounds__(256) void logits_kernel(const u16* __restrict__ qb, const u16* __restrict__ kb,
                                                     const float* __restrict__ MQ, const float* __restrict__ MK,
                                                     const u16* __restrict__ C1r, const u16* __restrict__ Mf,
                                                     const float* __restrict__ Rb, u16* __restrict__ L,
                                                     int n0) {
  __shared__ __align__(16) u16 AsH[4096], AsL[4096], BsH[4096], BsL[4096];
  const int tid = threadIdx.x, nl = blockIdx.z, n = n0 + nl, b = n >> 4;
  const int lane = tid & 63, wv = tid >> 6, wr = wv >> 1, wc = wv & 1;
  const int m = lane & 15, quad = lane >> 4;
  const size_t qa = ((size_t)n * 1024 + blockIdx.y * 128) * 64;
  const size_t ka = ((size_t)n * 1024 + blockIdx.x * 128) * 64;
  const size_t mqa = ((size_t)nl * 1024 + blockIdx.y * 128) * 64;
  const size_t mka = ((size_t)nl * 1024 + blockIdx.x * 128) * 64;
  const size_t ca = ((size_t)nl * 1024 + blockIdx.y * 128) * 512;
  const size_t ma = ((size_t)b * 1024 + blockIdx.x * 128) * 512;
  floatx4 acc[4][4];
  acc_zero(acc);
  for (int k0 = 0; k0 < 64; k0 += 32) {  // content QK^T bpe (bf16)
    __syncthreads();
    stage_u16(qb + qa + k0, 64, AsH, tid);
    stage_u16(kb + ka + k0, 64, BsH, tid);
    __syncthreads();
    mma_bf16(AsH, BsH, wr, wc, m, quad, acc);
  }
  for (int k0 = 0; k0 < 64; k0 += 32) {  // (MQ)(MK)^T fused content (Dekker)
    __syncthreads();
    stage_f32_split(MQ + mqa + k0, 64, AsH, AsL, tid);
    stage_f32_split(MK + mka + k0, 64, BsH, BsL, tid);
    __syncthreads();
    mma_split(AsH, AsL, BsH, BsL, wr, wc, m, quad, acc);
  }
  for (int k0 = 0; k0 < 512; k0 += 32) {  // M Rel M^T part 2: C1r @ Mf^T (fp16)
    __syncthreads();
    stage_u16(C1r + ca + k0, 512, AsH, tid);
    stage_u16(Mf + ma + k0, 512, BsH, tid);
    __syncthreads();
    mma_f16(AsH, BsH, wr, wc, m, quad, acc);
  }
  const int q0 = blockIdx.y * 128 + wr * 64 + quad * 4;
  const int k0c = blockIdx.x * 128 + wc * 64 + m;
#pragma unroll
  for (int rt = 0; rt < 4; ++rt)
#pragma unroll
    for (int ct = 0; ct < 4; ++ct) {
      int kc = k0c + ct * 16;
#pragma unroll
      for (int rg = 0; rg < 4; ++rg) {
        int q = q0 + rt * 16 + rg;
        int id = kc - q; id = id < -16 ? -16 : (id > 16 ? 16 : id); id += 16;
        float val = acc[rt][ct][rg] + Rb[((size_t)n * 1024 + q) * 33 + id];
        L[((size_t)nl * 1024 + q) * 1024 + kc] = f2h_bits(val);
      }
    }
}

// ---------------- softmax + PV (online; fp16 logits in A-frag layout) ----------
__global__ __launch_bounds__(256) void softmax_pv_kernel(const u16* __restrict__ L,
                                                         const u16* __restrict__ VT,
                                                         u16* __restrict__ AO, int n0) {
  __shared__ __align__(16) u16 Vs[4][2048];
  const int tid = threadIdx.x, lane = tid & 63, wv = tid >> 6;
  const int m = lane & 15, quad = lane >> 4;
  const int nl = blockIdx.y, n = n0 + nl, qt = blockIdx.x;
  const int qrow = qt * 64 + wv * 16 + m;
  const u16* Lrow = L + ((size_t)nl * 1024 + qrow) * 1024;
  const u16* Vbase = VT + (size_t)n * 64 * 1024;
  float mi = -1e30f, li = 0.f;
  floatx4 O[4];
  floatx4 z = {0.f, 0.f, 0.f, 0.f};
#pragma unroll
  for (int dt = 0; dt < 4; ++dt) O[dt] = z;

  for (int kt = 0; kt < 8; ++kt) {
    __syncthreads();
#pragma unroll
    for (int ct = 0; ct < 4; ++ct) {
      int o = tid * 16;
      int r = o >> 6, c = (o >> 4) & 3, sc = c ^ ((r >> 1) & 3);
      __builtin_amdgcn_global_load_lds(GAS(Vbase + (size_t)r * 1024 + kt * 128 + ct * 32 + sc * 8),
                                       LAS((char*)Vs[ct] + o), 16, 0, 0);
    }
    __syncthreads();

    float vals[4][8];
#pragma unroll
    for (int ct = 0; ct < 4; ++ct) {
      union { short8 s; _Float16 h[8]; } u;
      u.s = *(const short8*)(Lrow + kt * 128 + ct * 32 + quad * 8);
#pragma unroll
      for (int j = 0; j < 8; ++j) vals[ct][j] = (float)u.h[j];
    }
    float tmax = vals[0][0];
#pragma unroll
    for (int ct = 0; ct < 4; ++ct)
#pragma unroll
      for (int j = 0; j < 8; ++j) tmax = fmaxf(tmax, vals[ct][j]);
    tmax = fmaxf(tmax, __shfl_xor(tmax, 16));
    tmax = fmaxf(tmax, __shfl_xor(tmax, 32));
    float mnew = fmaxf(mi, tmax);
    float alpha = __expf(mi - mnew);
    float pv[4][8];
    float tsum = 0.f;
#pragma unroll
    for (int ct = 0; ct < 4; ++ct)
#pragma unroll
      for (int j = 0; j < 8; ++j) { pv[ct][j] = __expf(vals[ct][j] - mnew); tsum += pv[ct][j]; }
    tsum += __shfl_xor(tsum, 16);
    tsum += __shfl_xor(tsum, 32);
    li = li * alpha + tsum;
    mi = mnew;

    float ar[4];
#pragma unroll
    for (int rg = 0; rg < 4; ++rg) ar[rg] = __shfl(alpha, quad * 4 + rg);
#pragma unroll
    for (int dt = 0; dt < 4; ++dt)
#pragma unroll
      for (int rg = 0; rg < 4; ++rg) O[dt][rg] *= ar[rg];

    short8 pf[4];
#pragma unroll
    for (int ct = 0; ct < 4; ++ct) {
      union { short8 s; u16 us[8]; } up;
#pragma unroll
      for (int j = 0; j < 8; ++j) up.us[j] = f2bf(pv[ct][j]);
      pf[ct] = up.s;
    }
#pragma unroll
    for (int ct = 0; ct < 4; ++ct)
#pragma unroll
      for (int dt = 0; dt < 4; ++dt) {
        short8 vf = frag_ld(Vs[ct], dt * 16 + m, quad);
        O[dt] = __builtin_amdgcn_mfma_f32_16x16x32_bf16(pf[ct], vf, O[dt], 0, 0, 0);
      }
  }

  float linv = 1.f / li;
  float lr[4];
#pragma unroll
  for (int rg = 0; rg < 4; ++rg) lr[rg] = __shfl(linv, quad * 4 + rg);
  const int b = n >> 4, h = n & 15;
#pragma unroll
  for (int dt = 0; dt < 4; ++dt)
#pragma unroll
    for (int rg = 0; rg < 4; ++rg) {
      int q = qt * 64 + wv * 16 + quad * 4 + rg;
      float ov = O[dt][rg] * lr[rg];
      AO[((size_t)q * 4 + b) * 1024 + h * 64 + dt * 16 + m] = f2bf(ov);
    }
}

// ---------------- output projection: out = AO @ Wo^T + bo  (fp32 out) ----------
__global__ __launch_bounds__(256) void outproj_kernel(const u16* __restrict__ AO, const float* __restrict__ Wo,
                                                      const u16* __restrict__ Wob, int prep,
                                                      const float* __restrict__ bo, float* __restrict__ out) {
  __shared__ __align__(16) u16 As[4096], Bs[4096];
  const int tid = threadIdx.x;
  const int lane = tid & 63, wv = tid >> 6, wr = wv >> 1, wc = wv & 1;
  const int m = lane & 15, quad = lane >> 4;
  const u16* A = AO + (size_t)blockIdx.y * 128 * 1024;
  const size_t brow = (size_t)blockIdx.x * 128 * 1024;
  floatx4 acc[4][4];
  acc_zero(acc);
  for (int k0 = 0; k0 < 1024; k0 += 32) {
    __syncthreads();
    stage_u16(A + k0, 1024, As, tid);
    if (prep) stage_u16(Wob + brow + k0, 1024, Bs, tid);
    else      stage_f32_bf(Wo + brow + k0, 1024, Bs, tid);
    __syncthreads();
    mma_bf16(As, Bs, wr, wc, m, quad, acc);
  }
  const int r0 = blockIdx.y * 128 + wr * 64 + quad * 4;
  const int c0 = blockIdx.x * 128 + wc * 64 + m;
#pragma unroll
  for (int rt = 0; rt < 4; ++rt)
#pragma unroll
    for (int ct = 0; ct < 4; ++ct) {
      int col = c0 + ct * 16;
      float bi = bo[col];
#pragma unroll
      for (int rg = 0; rg < 4; ++rg) {
        int row = r0 + rt * 16 + rg;
        out[(size_t)row * 1024 + col] = acc[rt][ct][rg] + bi;
      }
    }
}

extern "C" void kernel_launch(void* const* d_in, const int* in_sizes, int n_in,
                              void* d_out, int out_size, void* d_ws, size_t ws_size,
                              hipStream_t stream) {
  const float* query_bpe = (const float*)d_in[0];
  const float* query_word = (const float*)d_in[1];
  const float* mapping = (const float*)d_in[2];
  const float* Wq_bpe = (const float*)d_in[3];
  const float* bq_bpe = (const float*)d_in[4];
  const float* Wk_bpe = (const float*)d_in[5];
  const float* bk_bpe = (const float*)d_in[6];
  const float* Wq_word = (const float*)d_in[7];
  const float* bq_word = (const float*)d_in[8];
  const float* Wk_word = (const float*)d_in[9];
  const float* bk_word = (const float*)d_in[10];
  const float* Wv = (const float*)d_in[11];
  const float* bv = (const float*)d_in[12];
  const float* Wo = (const float*)d_in[13];
  const float* bo = (const float*)d_in[14];
  const float* relk = (const float*)d_in[15];

  char* ws = (char*)d_ws;
  size_t off = 0;
  u16* q_bpe = (u16*)(ws + off); off += 8388608;   // [64][1024][64] bf16
  u16* k_bpe = (u16*)(ws + off); off += 8388608;
  u16* VTb   = (u16*)(ws + off); off += 8388608;   // [64][64][1024] bf16
  u16* qwT_h = (u16*)(ws + off); off += 4194304;   // [64][64][512] bf16 hi (transposed)
  u16* qwT_l = (u16*)(ws + off); off += 4194304;
  u16* kwT_h = (u16*)(ws + off); off += 4194304;
  u16* kwT_l = (u16*)(ws + off); off += 4194304;
  u16* M_h   = (u16*)(ws + off); off += 4194304;   // [4][1024][512] bf16
  u16* M_l   = (u16*)(ws + off); off += 4194304;
  u16* M_f   = (u16*)(ws + off); off += 4194304;   // fp16
  float* R_word = (float*)(ws + off); off += 4325376;  // [64][512][33]
  float* R_bpe  = (float*)(ws + off); off += 8650752;  // [64][1024][33]
  u16* AO    = (u16*)(ws + off); off += 8388608;   // [4096][1024] bf16
  u16* Wo_bf = (u16*)(ws + off); off += 2097152;   // Wo bf16 (read at the very end)
  const size_t fixed_end = off;                    // ~79.6 MB

  // Union region: transient prep buffers (30 MB, dead after proj_all) overlap
  // the per-chunk loop buffers (NC*4 MB). Stream serialization makes this safe.
  const size_t avail = (ws_size > fixed_end) ? ws_size - fixed_end : 0;
  const int prep = avail >= 31457280 ? 1 : 0;
  const size_t per_nc = 4194304;  // RelT 0.5 + C1r 1 + L(fp16) 2 + MQ 0.25 + MK 0.25
  int NC = 1;
  for (int c = 64; c >= 1; c >>= 1) {
    if ((size_t)c * per_nc <= avail) { NC = c; break; }
  }
  char* vb = ws + fixed_end;
  // loop buffers
  u16* RelT  = (u16*)(vb);
  u16* C1r   = (u16*)(vb + (size_t)NC * 524288);
  u16* L_c   = (u16*)(vb + (size_t)NC * 1572864);
  float* MQ  = (float*)(vb + (size_t)NC * 3670016);
  float* MK  = (float*)(vb + (size_t)NC * 3932160);
  // prep buffers (same bytes, earlier in time)
  u16* Xb    = (u16*)(vb);               // 8 MB  query_bpe bf16
  u16* Wqb   = (u16*)(vb + 8388608);     // 2 MB
  u16* Wkb   = (u16*)(vb + 10485760);
  u16* Wvb   = (u16*)(vb + 12582912);
  u16* Xw_h  = (u16*)(vb + 14680064);    // 4 MB
  u16* Xw_l  = (u16*)(vb + 18874368);
  u16* Wqw_h = (u16*)(vb + 23068672);    // 2 MB
  u16* Wqw_l = (u16*)(vb + 25165824);
  u16* Wkw_h = (u16*)(vb + 27262976);
  u16* Wkw_l = (u16*)(vb + 29360128);    // end 30 MB

  if (prep) {
    CvtB cb = {};
    cb.src[0] = query_bpe; cb.dst[0] = Xb;    cb.n8[0] = 524288;
    cb.src[1] = Wq_bpe;    cb.dst[1] = Wqb;   cb.n8[1] = 131072;
    cb.src[2] = Wk_bpe;    cb.dst[2] = Wkb;   cb.n8[2] = 131072;
    cb.src[3] = Wv;        cb.dst[3] = Wvb;   cb.n8[3] = 131072;
    cb.src[4] = Wo;        cb.dst[4] = Wo_bf; cb.n8[4] = 131072;
    cvt_bf_kernel<<<dim3(2048, 1, 5), 256, 0, stream>>>(cb);
    CvtS cs = {};
    cs.src[0] = query_word; cs.dh[0] = Xw_h;  cs.dl[0] = Xw_l;  cs.n8[0] = 262144;
    cs.src[1] = Wq_word;    cs.dh[1] = Wqw_h; cs.dl[1] = Wqw_l; cs.n8[1] = 131072;
    cs.src[2] = Wk_word;    cs.dh[2] = Wkw_h; cs.dl[2] = Wkw_l; cs.n8[2] = 131072;
    cvt_split_kernel<<<dim3(1024, 1, 3), 256, 0, stream>>>(cs);
  }

  PAll pa = {};
  pa.prep = prep;
  pa.Xf[0] = query_bpe;  pa.Wf[0] = Wq_bpe;  pa.Xh[0] = Xb;   pa.Wh[0] = Wqb;
  pa.bias[0] = bq_bpe;  pa.scale[0] = 0.125f; pa.dh[0] = q_bpe; pa.T[0] = 1024; pa.md[0] = 0;
  pa.Xf[1] = query_bpe;  pa.Wf[1] = Wk_bpe;  pa.Xh[1] = Xb;   pa.Wh[1] = Wkb;
  pa.bias[1] = bk_bpe;  pa.scale[1] = 1.0f;   pa.dh[1] = k_bpe; pa.T[1] = 1024; pa.md[1] = 0;
  pa.Xf[2] = query_bpe;  pa.Wf[2] = Wv;      pa.Xh[2] = Xb;   pa.Wh[2] = Wvb;
  pa.bias[2] = bv;      pa.scale[2] = 1.0f;   pa.dh[2] = VTb;   pa.T[2] = 1024; pa.md[2] = 1;
  pa.Xf[3] = query_word; pa.Wf[3] = Wq_word; pa.Xh[3] = Xw_h; pa.Xl[3] = Xw_l;
  pa.Wh[3] = Wqw_h; pa.Wl[3] = Wqw_l;
  pa.bias[3] = bq_word; pa.scale[3] = 0.125f; pa.dh[3] = qwT_h; pa.dl[3] = qwT_l; pa.T[3] = 512; pa.md[3] = 2;
  pa.Xf[4] = query_word; pa.Wf[4] = Wk_word; pa.Xh[4] = Xw_h; pa.Xl[4] = Xw_l;
  pa.Wh[4] = Wkw_h; pa.Wl[4] = Wkw_l;
  pa.bias[4] = bk_word; pa.scale[4] = 1.0f;   pa.dh[4] = kwT_h; pa.dl[4] = kwT_l; pa.T[4] = 512; pa.md[4] = 2;
  proj_all_kernel<<<dim3(8, 32, 5), 256, 0, stream>>>(pa);

  msplit_kernel<<<dim3(4 * 1024 * 512 / 256), 256, 0, stream>>>(mapping, M_h, M_l, M_f);

  rel_bpe_kernel<<<dim3(64 * 1024 / 256), 256, 0, stream>>>(q_bpe, relk, R_bpe);
  rel_word_kernel<<<dim3(64 * 512 / 256), 256, 0, stream>>>(qwT_h, qwT_l, relk, R_word);

  for (int n0 = 0; n0 < 64; n0 += NC) {
    relmat_kernel<<<dim3(NC * 1024), 256, 0, stream>>>(R_word, RelT, n0);
    mqk_kernel<<<dim3(8, NC), 256, 0, stream>>>(M_h, M_l, qwT_h, qwT_l, kwT_h, kwT_l, MQ, MK, n0);
    stage1_kernel<<<dim3(4, 8, NC), 256, 0, stream>>>(M_f, RelT, C1r, n0);
    logits_kernel<<<dim3(8, 8, NC), 256, 0, stream>>>(q_bpe, k_bpe, MQ, MK, C1r, M_f, R_bpe, L_c, n0);
    softmax_pv_kernel<<<dim3(16, NC), 256, 0, stream>>>(L_c, VTb, AO, n0);
  }

  outproj_kernel<<<dim3(8, 32), 256, 0, stream>>>(AO, Wo, Wo_bf, prep, bo, (float*)d_out);
}